// Round 12
// baseline (1687.027 us; speedup 1.0000x reference)
//
#include <hip/hip_runtime.h>
#include <hip/hip_bf16.h>
#include <math.h>

// Problem constants
#define NTOT 4096      // B*N nodes
#define NEDGE 65536    // E edges
#define BSZ 64         // batch
#define NN 64          // nodes per trajectory
#define HDIM 1024      // LSTM hidden
#define TIN 10
#define TOUT 6
#define FRAME_ELEMS (NTOT * 2)   // 8192 floats per frame

typedef short s16x8 __attribute__((ext_vector_type(8)));
typedef float f32x4 __attribute__((ext_vector_type(4)));

__device__ __forceinline__ unsigned short f2bf(float f) {
    union { float f; unsigned u; } x; x.f = f;
    unsigned r = x.u + 0x7fffu + ((x.u >> 16) & 1u);
    return (unsigned short)(r >> 16);
}

// ==================== combined weight transpose (task list) ====================
struct TT { const float* W; float* WT; int NO; int K; int toff; };
struct TT8 { TT t[8]; };

__global__ __launch_bounds__(256) void transpose_all(TT8 tasks) {
    int bid = blockIdx.x;
    int ti = 0;
    #pragma unroll
    for (int j = 1; j < 8; ++j) if (bid >= tasks.t[j].toff) ti = j;
    TT tk = tasks.t[ti];
    int local = bid - tk.toff;
    int tilesK = tk.K >> 5;
    int kb = local % tilesK, nb = local / tilesK;
    int k0 = kb * 32, n0 = nb * 32;
    __shared__ float t[32][33];
    int tx = threadIdx.x & 31, ty = threadIdx.x >> 5;  // 32 x 8
    #pragma unroll
    for (int i = 0; i < 4; ++i)
        t[ty + i * 8][tx] = tk.W[(size_t)(n0 + ty + i * 8) * tk.K + k0 + tx];
    __syncthreads();
    #pragma unroll
    for (int i = 0; i < 4; ++i)
        tk.WT[(size_t)(k0 + ty + i * 8) * tk.NO + n0 + tx] = t[tx][ty + i * 8];
}

// ==================== batched GCN over 10 input frames ====================

__global__ void bgcn_init_xw(const float* __restrict__ feat, const float* __restrict__ wg,
                             float* __restrict__ deg, float* __restrict__ xw) {
    int i = blockIdx.x * blockDim.x + threadIdx.x;
    if (i >= 10 * NTOT) return;
    deg[i] = 1.0f;
    float x0 = feat[i * 2], x1 = feat[i * 2 + 1];
    xw[i * 2]     = x0 * wg[0] + x1 * wg[1];
    xw[i * 2 + 1] = x0 * wg[2] + x1 * wg[3];
}

__global__ void bgcn_count(const int* __restrict__ ei, float* __restrict__ deg) {
    int e = blockIdx.x * blockDim.x + threadIdx.x;
    if (e >= 10 * NEDGE) return;
    int t = e >> 16, el = e & 65535;
    int dst = ei[t * 2 * NEDGE + NEDGE + el];
    atomicAdd(&deg[t * NTOT + dst], 1.0f);
}

__global__ void bgcn_node(const float* __restrict__ bg, float* __restrict__ deg,
                          const float* __restrict__ xw, float* __restrict__ gT_all) {
    int i = blockIdx.x * blockDim.x + threadIdx.x;
    if (i >= 10 * NTOT) return;
    float dinv = rsqrtf(deg[i]);
    deg[i] = dinv;
    int t = i >> 12, node = i & 4095;
    int b = node >> 6, nn = node & 63;
    float w2 = dinv * dinv;
    gT_all[t * 8192 + (nn * 2 + 0) * 64 + b] = xw[i * 2]     * w2 + bg[0];
    gT_all[t * 8192 + (nn * 2 + 1) * 64 + b] = xw[i * 2 + 1] * w2 + bg[1];
}

// LDS-accumulated edge scatter: 8 blocks per frame
__global__ __launch_bounds__(256) void bgcn_scatter_lds(const int* __restrict__ ei,
                                                        const float* __restrict__ dinv,
                                                        const float* __restrict__ xw,
                                                        float* __restrict__ gT_all) {
    __shared__ float sg[8192];
    int t = blockIdx.x >> 3;
    int chunk = blockIdx.x & 7;
    for (int i = threadIdx.x; i < 8192; i += 256) sg[i] = 0.f;
    __syncthreads();
    const int* eis = ei + t * 2 * NEDGE;
    int e0 = chunk * 8192;
    for (int e = e0 + threadIdx.x; e < e0 + 8192; e += 256) {
        int s = eis[e];
        int d = eis[NEDGE + e];
        float w = dinv[t * NTOT + s] * dinv[t * NTOT + d];
        int b = d >> 6, nn = d & 63;
        atomicAdd(&sg[(nn * 2 + 0) * 64 + b], xw[(t * NTOT + s) * 2]     * w);
        atomicAdd(&sg[(nn * 2 + 1) * 64 + b], xw[(t * NTOT + s) * 2 + 1] * w);
    }
    __syncthreads();
    float* gt = gT_all + t * 8192;
    for (int i = threadIdx.x; i < 8192; i += 256) {
        float v = sg[i];
        if (v != 0.f) atomicAdd(&gt[i], v);
    }
}

// ==================== broadcast-x GEMM (round-6 proven: staged KC, 16 m per thread) ====================
// P[ks][n][m] = sum over k-chunk ks of in[m][k] * W[n][k].
// thread: nl = tid>>2 (n within 64-tile), q = tid&3 -> m in [q*16, q*16+16).
template<int KC>
__global__ __launch_bounds__(256) void gemm_bx3(
    const float* __restrict__ inT, const float* __restrict__ inT2,
    const float* __restrict__ WT,  const float* __restrict__ WT2,
    float* __restrict__ P, int NO, int SK1)
{
    constexpr int STG = (KC > 128) ? 128 : KC;
    __shared__ float xs[STG * 64];
    int tid = threadIdx.x;
    int ks = blockIdx.y;
    const float* xsrc; const float* wsrc;
    if (ks < SK1) { xsrc = inT  + (size_t)ks * KC * 64;         wsrc = WT  + (size_t)ks * KC * NO; }
    else          { xsrc = inT2 + (size_t)(ks - SK1) * KC * 64; wsrc = WT2 + (size_t)(ks - SK1) * KC * NO; }
    int nl = tid >> 2, q = tid & 3;
    int n = blockIdx.x * 64 + nl;
    const float* xq = xs + q * 16;
    float acc[16];
    #pragma unroll
    for (int j = 0; j < 16; ++j) acc[j] = 0.f;

    for (int kb = 0; kb < KC; kb += STG) {
        if (kb) __syncthreads();
        for (int i = tid; i < STG * 16; i += 256)
            ((float4*)xs)[i] = ((const float4*)(xsrc + (size_t)kb * 64))[i];
        __syncthreads();
        const float* wp = wsrc + (size_t)kb * NO + n;
        float wbuf[4];
        #pragma unroll
        for (int kk = 0; kk < 4; ++kk) wbuf[kk] = wp[(size_t)kk * NO];
        for (int k = 0; k < STG; k += 4) {
            float wn[4] = {0.f, 0.f, 0.f, 0.f};
            if (k + 4 < STG) {
                #pragma unroll
                for (int kk = 0; kk < 4; ++kk) wn[kk] = wp[(size_t)(k + 4 + kk) * NO];
            }
            #pragma unroll
            for (int kk = 0; kk < 4; ++kk) {
                const float* xrow = xq + (k + kk) * 64;
                float w = wbuf[kk];
                float4 x0 = *(const float4*)(xrow + 0);
                float4 x1 = *(const float4*)(xrow + 4);
                float4 x2 = *(const float4*)(xrow + 8);
                float4 x3 = *(const float4*)(xrow + 12);
                acc[0]  = fmaf(w, x0.x, acc[0]);  acc[1]  = fmaf(w, x0.y, acc[1]);
                acc[2]  = fmaf(w, x0.z, acc[2]);  acc[3]  = fmaf(w, x0.w, acc[3]);
                acc[4]  = fmaf(w, x1.x, acc[4]);  acc[5]  = fmaf(w, x1.y, acc[5]);
                acc[6]  = fmaf(w, x1.z, acc[6]);  acc[7]  = fmaf(w, x1.w, acc[7]);
                acc[8]  = fmaf(w, x2.x, acc[8]);  acc[9]  = fmaf(w, x2.y, acc[9]);
                acc[10] = fmaf(w, x2.z, acc[10]); acc[11] = fmaf(w, x2.w, acc[11]);
                acc[12] = fmaf(w, x3.x, acc[12]); acc[13] = fmaf(w, x3.y, acc[13]);
                acc[14] = fmaf(w, x3.z, acc[14]); acc[15] = fmaf(w, x3.w, acc[15]);
            }
            #pragma unroll
            for (int kk = 0; kk < 4; ++kk) wbuf[kk] = wn[kk];
        }
    }
    float* pp = P + ((size_t)ks * NO + n) * 64 + q * 16;
    *(float4*)(pp + 0)  = make_float4(acc[0],  acc[1],  acc[2],  acc[3]);
    *(float4*)(pp + 4)  = make_float4(acc[4],  acc[5],  acc[6],  acc[7]);
    *(float4*)(pp + 8)  = make_float4(acc[8],  acc[9],  acc[10], acc[11]);
    *(float4*)(pp + 12) = make_float4(acc[12], acc[13], acc[14], acc[15]);
}

// ==================== reduce partials + bias (+relu) -> aT (NO,64) ====================
__global__ void reduce_relu_kernel(const float* __restrict__ P,
                                   const float* __restrict__ bias,
                                   float* __restrict__ aT,
                                   int NO, int SK, int relu) {
    int idx = blockIdx.x * blockDim.x + threadIdx.x;
    if (idx >= NO * 64) return;
    int n = idx >> 6;
    float v = bias[n];
    for (int ks = 0; ks < SK; ++ks) v += P[(size_t)ks * NO * 64 + idx];
    if (relu) v = fmaxf(v, 0.f);
    aT[idx] = v;
}

// ==================== LSTM pointwise from 9 partials (+ optional bf16 h-stash) ====================
__global__ void lstm_update2(const float* __restrict__ P,
                             const float* __restrict__ b_ih, const float* __restrict__ b_hh,
                             float* __restrict__ hT, float* __restrict__ cT,
                             unsigned short* __restrict__ stash, int mbase) {
    int t = blockIdx.x * blockDim.x + threadIdx.x;
    if (t >= HDIM * BSZ) return;
    int j = t >> 6, b = t & 63;
    float g4[4];
    #pragma unroll
    for (int gi = 0; gi < 4; ++gi) {
        int row = gi * HDIM + j;
        float v = b_ih[row] + b_hh[row];
        size_t base = (size_t)row * 64 + b;
        #pragma unroll
        for (int ks = 0; ks < 9; ++ks) v += P[(size_t)ks * 4096 * 64 + base];
        g4[gi] = v;
    }
    float si = 1.f / (1.f + expf(-g4[0]));
    float sf = 1.f / (1.f + expf(-g4[1]));
    float gg = tanhf(g4[2]);
    float so = 1.f / (1.f + expf(-g4[3]));
    float cn = sf * cT[t] + si * gg;
    cT[t] = cn;
    float h = so * tanhf(cn);
    hT[t] = h;
    if (stash) stash[(size_t)(mbase + b) * HDIM + j] = f2bf(h);
}

// ==================== finalize3: reduce l5 partials + l6 GEMM + frame (+adj + dense GCN) ====================
// P: l5 partials (16, 512, 64). wt5: (512,128) = l6 W^T. block = trajectory, 128 threads.
__global__ void finalize3(const float* __restrict__ P, const float* __restrict__ b5,
                          const float* __restrict__ wt5, const float* __restrict__ b6,
                          const float* __restrict__ stats, const float* __restrict__ wg,
                          const float* __restrict__ bg,
                          float* __restrict__ frame, float* __restrict__ gT, int dec)
{
    int b = blockIdx.x;
    int n = threadIdx.x;   // 0..127
    __shared__ float a5[512];
    __shared__ float p[128];
    __shared__ float f0[NN], f1[NN], sxw0[NN], sxw1[NN], sdinv[NN];
    __shared__ int ex[NN];
    #pragma unroll
    for (int j = 0; j < 4; ++j) {
        int k = n * 4 + j;
        float v = b5[k];
        #pragma unroll 4
        for (int ks = 0; ks < 16; ++ks) v += P[((size_t)ks * 512 + k) * 64 + b];
        a5[k] = fmaxf(v, 0.f);
    }
    __syncthreads();
    float acc = b6[n];
    for (int k = 0; k < 512; ++k) acc = fmaf(a5[k], wt5[k * 128 + n], acc);
    p[n] = acc;
    frame[b * 128 + n] = acc;
    if (!dec) return;
    __syncthreads();
    int i = n;
    if (i < NN) {
        float p0 = p[i * 2], p1 = p[i * 2 + 1];
        float d0 = p0 * stats[0] + stats[2];
        float d1 = p1 * stats[1] + stats[3];
        f0[i] = d0; f1[i] = d1;
        ex[i] = (d0 > 0.04f) && (d1 > 0.04f);
        sxw0[i] = p0 * wg[0] + p1 * wg[1];
        sxw1[i] = p0 * wg[2] + p1 * wg[3];
    }
    __syncthreads();
    if (i < NN) {
        float fi0 = f0[i], fi1 = f1[i];
        int exi = ex[i];
        float deg = 0.f;
        for (int j = 0; j < NN; ++j) {
            float dx = fi0 - f0[j], dy = fi1 - f1[j];
            float a = (i == j) ? 1.0f :
                      ((dx * dx + dy * dy <= 100.0f && exi && ex[j]) ? 1.0f : 0.0f);
            deg += a;
        }
        sdinv[i] = rsqrtf(deg);
    }
    __syncthreads();
    if (i < NN) {
        float fi0 = f0[i], fi1 = f1[i];
        int exi = ex[i];
        float a0 = 0.f, a1 = 0.f;
        for (int j = 0; j < NN; ++j) {
            float dx = fi0 - f0[j], dy = fi1 - f1[j];
            float a = (i == j) ? 1.0f :
                      ((dx * dx + dy * dy <= 100.0f && exi && ex[j]) ? 1.0f : 0.0f);
            float an = a * sdinv[j];
            a0 += an * sxw0[j];
            a1 += an * sxw1[j];
        }
        float di = sdinv[i];
        gT[(i * 2 + 0) * 64 + b] = a0 * di + bg[0];
        gT[(i * 2 + 1) * 64 + b] = a1 * di + bg[1];
    }
}

// ==================== combined bf16 pack (task list) ====================
struct PTasks {
    const float* W[6]; unsigned short* Bp[6]; int K[6]; int goff[7];
};
__global__ void pack_all(PTasks pt) {
    int g = blockIdx.x * blockDim.x + threadIdx.x;
    if (g >= pt.goff[6]) return;
    int l = 0;
    #pragma unroll
    for (int j = 1; j < 6; ++j) if (g >= pt.goff[j]) l = j;
    int local = g - pt.goff[l];
    int kgs = pt.K[l] >> 3;
    int kg = local % kgs;
    int n  = local / kgs;
    const float* src = pt.W[l] + (size_t)n * pt.K[l] + (size_t)kg * 8;
    unsigned short* dst = pt.Bp[l] + ((size_t)kg * (pt.goff[l + 1] - pt.goff[l]) / kgs + n) * 8;
    #pragma unroll
    for (int j = 0; j < 8; ++j) dst[j] = f2bf(src[j]);
}

// ==================== batched MFMA MLP layer v2 + split-K (blockIdx.z) ====================
// If accbuf != null: partial sums atomicAdd'ed into accbuf[m*NO+n] (no bias/relu).
// Else: direct epilogue (bias, optional relu, outb/frames) — use only with gridDim.z==1.
__global__ __launch_bounds__(256) void gemm_mfma2(
    const unsigned short* __restrict__ inb,
    const unsigned short* __restrict__ Bp,
    const float* __restrict__ bias,
    unsigned short* __restrict__ outb,
    float* __restrict__ frames,
    float* __restrict__ accbuf,
    int K, int KC, int NO, int relu)
{
    __shared__ unsigned short A[64][72];
    int tid = threadIdx.x;
    int lane = tid & 63;
    int w = tid >> 6;
    int m0 = blockIdx.y * 64;
    int nb = blockIdx.x * 64;
    int koff = blockIdx.z * KC;
    int l15 = lane & 15;
    int lq  = lane >> 4;
    int n = nb + w * 16 + l15;
    int sm = tid >> 3, skq = tid & 7;
    const unsigned short* bpb = Bp + (size_t)(koff >> 3) * NO * 8;
    f32x4 acc[4] = {};

    {
        s16x8 a0 = *(const s16x8*)&inb[(size_t)(m0 + sm) * K + koff + skq * 8];
        s16x8 a1 = *(const s16x8*)&inb[(size_t)(m0 + sm + 32) * K + koff + skq * 8];
        *(s16x8*)&A[sm][skq * 8] = a0;
        *(s16x8*)&A[sm + 32][skq * 8] = a1;
    }
    __syncthreads();
    s16x8 b0 = *(const s16x8*)&bpb[((size_t)(0 + lq) * NO + n) * 8];
    s16x8 b1 = *(const s16x8*)&bpb[((size_t)(4 + lq) * NO + n) * 8];

    int nk = KC >> 6;
    for (int t = 0; t < nk; ++t) {
        s16x8 na0, na1, nb0, nb1;
        bool more = (t + 1 < nk);
        if (more) {
            int ko = koff + (t + 1) * 64;
            na0 = *(const s16x8*)&inb[(size_t)(m0 + sm) * K + ko + skq * 8];
            na1 = *(const s16x8*)&inb[(size_t)(m0 + sm + 32) * K + ko + skq * 8];
            int kg = (t + 1) * 8;
            nb0 = *(const s16x8*)&bpb[((size_t)(kg + lq) * NO + n) * 8];
            nb1 = *(const s16x8*)&bpb[((size_t)(kg + 4 + lq) * NO + n) * 8];
        }
        #pragma unroll
        for (int s = 0; s < 4; ++s) {
            s16x8 af = *(const s16x8*)&A[s * 16 + l15][lq * 8];
            acc[s] = __builtin_amdgcn_mfma_f32_16x16x32_bf16(af, b0, acc[s], 0, 0, 0);
        }
        #pragma unroll
        for (int s = 0; s < 4; ++s) {
            s16x8 af = *(const s16x8*)&A[s * 16 + l15][32 + lq * 8];
            acc[s] = __builtin_amdgcn_mfma_f32_16x16x32_bf16(af, b1, acc[s], 0, 0, 0);
        }
        if (more) {
            __syncthreads();
            *(s16x8*)&A[sm][skq * 8] = na0;
            *(s16x8*)&A[sm + 32][skq * 8] = na1;
            __syncthreads();
            b0 = nb0; b1 = nb1;
        }
    }
    if (accbuf) {
        #pragma unroll
        for (int s = 0; s < 4; ++s) {
            #pragma unroll
            for (int r = 0; r < 4; ++r) {
                int m = m0 + s * 16 + lq * 4 + r;
                atomicAdd(&accbuf[(size_t)m * NO + n], acc[s][r]);
            }
        }
        return;
    }
    float bn = bias[n];
    #pragma unroll
    for (int s = 0; s < 4; ++s) {
        #pragma unroll
        for (int r = 0; r < 4; ++r) {
            int m = m0 + s * 16 + lq * 4 + r;
            float v = acc[s][r] + bn;
            if (relu) v = fmaxf(v, 0.f);
            if (outb) outb[(size_t)m * NO + n] = f2bf(v);
            if (frames && m < 576) {
                int f = m >> 6, b = m & 63;
                frames[(size_t)f * FRAME_ELEMS + b * 128 + n] = v;
            }
        }
    }
}

// ==================== bias+relu+pack for split-K accumulated layers ====================
__global__ void packrelu_kernel(const float* __restrict__ acc, const float* __restrict__ bias,
                                unsigned short* __restrict__ outb, int NO) {
    int idx = blockIdx.x * blockDim.x + threadIdx.x;
    if (idx >= 576 * NO) return;
    int n = idx & (NO - 1);   // NO is a power of 2
    float v = acc[idx] + bias[n];
    outb[idx] = f2bf(fmaxf(v, 0.f));
}

// ==================== host ====================

extern "C" void kernel_launch(void* const* d_in, const int* in_sizes, int n_in,
                              void* d_out, int out_size, void* d_ws, size_t ws_size,
                              hipStream_t stream) {
    const float* feat   = (const float*)d_in[0];
    const int*   ei_in  = (const int*)d_in[1];
    const float* stats  = (const float*)d_in[4];
    const float* w_gcn  = (const float*)d_in[5];
    const float* b_gcn  = (const float*)d_in[6];
    const float* w_ih   = (const float*)d_in[7];
    const float* w_hh   = (const float*)d_in[8];
    const float* b_ih   = (const float*)d_in[9];
    const float* b_hh   = (const float*)d_in[10];
    const float* wm[6], *bm[6];
    for (int i = 0; i < 6; ++i) { wm[i] = (const float*)d_in[11 + 2*i]; bm[i] = (const float*)d_in[12 + 2*i]; }
    const int mlp_K[6]  = {1024, 2048, 4096, 2048, 1024, 512};
    const int mlp_NO[6] = {2048, 4096, 2048, 1024, 512, 128};

    float* out = (float*)d_out;
    float* ws  = (float*)d_ws;

    // ---------- workspace layout (floats) ----------
    size_t off = 0;
    float* wt_ih = ws + off; off += (size_t)128 * 4096;
    float* wt_hh = ws + off; off += (size_t)1024 * 4096;
    float* wt[6];
    const size_t wt_sz[6] = {(size_t)1024*2048, (size_t)2048*4096, (size_t)4096*2048,
                             (size_t)2048*1024, (size_t)1024*512, (size_t)512*128};
    for (int i = 0; i < 6; ++i) { wt[i] = ws + off; off += wt_sz[i]; }
    float* P      = ws + off; off += (size_t)32 * 2048 * 64;  // 4.19M floats
    float* gT_all = ws + off; off += (size_t)10 * 128 * 64;
    float* gT_dec = ws + off; off += 8192;
    float* hT     = ws + off; off += 65536;
    float* cT     = ws + off; off += 65536;
    float* aT1    = ws + off; off += 131072;
    float* aT2    = ws + off; off += 262144;
    float* aT3    = aT1;       // aliases: aT1 dead after l2 stage reads it
    float* aT4    = aT2;       // aliases: aT2 dead after l3 stage reads it
    float* inb1f  = ws + off; off += 147456;                  // 576*1024 bf16 (overlaps deg/xw)
    float* deg    = inb1f;                                    // 40960 floats, dead before inb1 written
    float* xw     = inb1f + 40960;                            // 81920 floats, ditto
    size_t need_bytes = off * sizeof(float);
    if (ws_size < need_bytes) return;

    // bf16 views: inb2..6 alias P (dead during final MFMA phase); 11.2MB <= 16.8MB
    unsigned short* inb1 = (unsigned short*)inb1f;
    unsigned short* inb2 = (unsigned short*)P;
    unsigned short* inb3 = inb2 + (size_t)576 * 2048;
    unsigned short* inb4 = inb3 + (size_t)576 * 4096;
    unsigned short* inb5 = inb4 + (size_t)576 * 2048;
    unsigned short* inb6 = inb5 + (size_t)576 * 1024;
    unsigned short* Bp[6];
    {
        unsigned short* base = (unsigned short*)wt[0];
        size_t boff = 0;
        for (int l = 0; l < 6; ++l) { Bp[l] = base + boff; boff += (size_t)mlp_NO[l] * mlp_K[l]; }
    }
    // split-K fp32 accumulator aliases wt_hh (fp32 LSTM weights dead after step 14)
    float* accbuf = wt_hh;   // 4.19M floats >= 576*4096

    hipMemsetAsync(hT, 0, 2 * 65536 * sizeof(float), stream);
    hipMemcpyAsync(out, feat, FRAME_ELEMS * sizeof(float), hipMemcpyDeviceToDevice, stream);

    // ---------- upfront: all weight transposes in one launch ----------
    {
        TT8 tasks;
        const float* Wp[8] = {w_ih, w_hh, wm[0], wm[1], wm[2], wm[3], wm[4], wm[5]};
        float* WTp[8] = {wt_ih, wt_hh, wt[0], wt[1], wt[2], wt[3], wt[4], wt[5]};
        int NOs[8] = {4096, 4096, 2048, 4096, 2048, 1024, 512, 128};
        int Ks[8]  = {128, 1024, 1024, 2048, 4096, 2048, 1024, 512};
        int toff = 0;
        for (int j = 0; j < 8; ++j) {
            tasks.t[j] = {Wp[j], WTp[j], NOs[j], Ks[j], toff};
            toff += (Ks[j] >> 5) * (NOs[j] >> 5);
        }
        transpose_all<<<toff, 256, 0, stream>>>(tasks);
    }

    // ---------- upfront: batched GCN for all 10 input frames ----------
    bgcn_init_xw<<<10 * NTOT / 256, 256, 0, stream>>>(feat, w_gcn, deg, xw);
    bgcn_count<<<10 * NEDGE / 256, 256, 0, stream>>>(ei_in, deg);
    bgcn_node<<<10 * NTOT / 256, 256, 0, stream>>>(b_gcn, deg, xw, gT_all);
    bgcn_scatter_lds<<<80, 256, 0, stream>>>(ei_in, deg, xw, gT_all);

    // ---------- 15 serial steps ----------
    for (int s = 0; s < 15; ++s) {
        const float* gT_s = (s <= 9) ? (gT_all + (size_t)s * 8192) : gT_dec;

        // LSTM: ks 0..7 = hh chunks (K=1024, KC=128), ks 8 = ih (K=128)
        gemm_bx3<128><<<dim3(64, 9), 256, 0, stream>>>(hT, gT_s, wt_hh, wt_ih, P, 4096, 8);
        lstm_update2<<<HDIM * BSZ / 256, 256, 0, stream>>>(
            P, b_ih, b_hh, hT, cT, (s <= 8) ? inb1 : nullptr, s * 64);

        if (s >= 9) {
            float* frame = out + (size_t)(s + 1) * FRAME_ELEMS;
            // l1: K=1024 NO=2048 KC=64 SK=16
            gemm_bx3<64><<<dim3(32, 16), 256, 0, stream>>>(hT, nullptr, wt[0], nullptr, P, 2048, 16);
            reduce_relu_kernel<<<2048 * 64 / 256, 256, 0, stream>>>(P, bm[0], aT1, 2048, 16, 1);
            // l2: K=2048 NO=4096 KC=256 (staged 2x128) SK=8
            gemm_bx3<256><<<dim3(64, 8), 256, 0, stream>>>(aT1, nullptr, wt[1], nullptr, P, 4096, 8);
            reduce_relu_kernel<<<4096 * 64 / 256, 256, 0, stream>>>(P, bm[1], aT2, 4096, 8, 1);
            // l3: K=4096 NO=2048 KC=256 (staged 2x128) SK=16
            gemm_bx3<256><<<dim3(32, 16), 256, 0, stream>>>(aT2, nullptr, wt[2], nullptr, P, 2048, 16);
            reduce_relu_kernel<<<2048 * 64 / 256, 256, 0, stream>>>(P, bm[2], aT3, 2048, 16, 1);
            // l4: K=2048 NO=1024 KC=128 SK=16
            gemm_bx3<128><<<dim3(16, 16), 256, 0, stream>>>(aT3, nullptr, wt[3], nullptr, P, 1024, 16);
            reduce_relu_kernel<<<1024 * 64 / 256, 256, 0, stream>>>(P, bm[3], aT4, 1024, 16, 1);
            // l5: K=1024 NO=512 KC=64 SK=16 (partials only; finalize3 reduces)
            gemm_bx3<64><<<dim3(8, 16), 256, 0, stream>>>(aT4, nullptr, wt[4], nullptr, P, 512, 16);
            // finalize: reduce l5 + l6 GEMM + frame write (+ adjacency + dense GCN)
            finalize3<<<BSZ, 128, 0, stream>>>(P, bm[4], wt[5], bm[5], stats, w_gcn, b_gcn,
                                               frame, gT_dec, (s < 14) ? 1 : 0);
        }
    }

    // ---------- batched encoder MLP (frames 1..9), bf16 MFMA, M=576, split-K ----------
    {
        PTasks pt;
        int goff = 0;
        for (int l = 0; l < 6; ++l) {
            pt.W[l] = wm[l]; pt.Bp[l] = Bp[l]; pt.K[l] = mlp_K[l];
            pt.goff[l] = goff;
            goff += mlp_NO[l] * (mlp_K[l] >> 3);
        }
        pt.goff[6] = goff;
        pack_all<<<(goff + 255) / 256, 256, 0, stream>>>(pt);
    }
    unsigned short* chain_in[6]  = {inb1, inb2, inb3, inb4, inb5, inb6};
    unsigned short* chain_out[6] = {inb2, inb3, inb4, inb5, inb6, nullptr};
    const int mlp_SK[6] = {2, 4, 8, 4, 2, 1};   // KC = K/SK = 512 everywhere
    for (int l = 0; l < 6; ++l) {
        int NO = mlp_NO[l], K = mlp_K[l], SK = mlp_SK[l], KC = K / SK;
        if (l < 5) {
            hipMemsetAsync(accbuf, 0, (size_t)576 * NO * sizeof(float), stream);
            gemm_mfma2<<<dim3(NO / 64, 9, SK), 256, 0, stream>>>(
                chain_in[l], Bp[l], bm[l], nullptr, nullptr, accbuf, K, KC, NO, 0);
            packrelu_kernel<<<(576 * NO + 255) / 256, 256, 0, stream>>>(
                accbuf, bm[l], chain_out[l], NO);
        } else {
            gemm_mfma2<<<dim3(NO / 64, 9, 1), 256, 0, stream>>>(
                chain_in[l], Bp[l], bm[l], nullptr, out + FRAME_ELEMS, nullptr, K, KC, NO, 0);
        }
    }
}

// Round 13
// 1594.807 us; speedup vs baseline: 1.0578x; 1.0578x over previous
//
#include <hip/hip_runtime.h>
#include <hip/hip_bf16.h>
#include <math.h>

// Problem constants
#define NTOT 4096      // B*N nodes
#define NEDGE 65536    // E edges
#define BSZ 64         // batch
#define NN 64          // nodes per trajectory
#define HDIM 1024      // LSTM hidden
#define TIN 10
#define TOUT 6
#define FRAME_ELEMS (NTOT * 2)   // 8192 floats per frame

typedef short s16x8 __attribute__((ext_vector_type(8)));
typedef float f32x4 __attribute__((ext_vector_type(4)));

__device__ __forceinline__ unsigned short f2bf(float f) {
    union { float f; unsigned u; } x; x.f = f;
    unsigned r = x.u + 0x7fffu + ((x.u >> 16) & 1u);
    return (unsigned short)(r >> 16);
}

// ==================== combined weight transpose (task list) ====================
struct TT { const float* W; float* WT; int NO; int K; int toff; };
struct TT8 { TT t[8]; };

__global__ __launch_bounds__(256) void transpose_all(TT8 tasks) {
    int bid = blockIdx.x;
    int ti = 0;
    #pragma unroll
    for (int j = 1; j < 8; ++j) if (bid >= tasks.t[j].toff) ti = j;
    TT tk = tasks.t[ti];
    int local = bid - tk.toff;
    int tilesK = tk.K >> 5;
    int kb = local % tilesK, nb = local / tilesK;
    int k0 = kb * 32, n0 = nb * 32;
    __shared__ float t[32][33];
    int tx = threadIdx.x & 31, ty = threadIdx.x >> 5;  // 32 x 8
    #pragma unroll
    for (int i = 0; i < 4; ++i)
        t[ty + i * 8][tx] = tk.W[(size_t)(n0 + ty + i * 8) * tk.K + k0 + tx];
    __syncthreads();
    #pragma unroll
    for (int i = 0; i < 4; ++i)
        tk.WT[(size_t)(k0 + ty + i * 8) * tk.NO + n0 + tx] = t[tx][ty + i * 8];
}

// ==================== batched GCN over 10 input frames ====================

__global__ void bgcn_init_xw(const float* __restrict__ feat, const float* __restrict__ wg,
                             float* __restrict__ deg, float* __restrict__ xw) {
    int i = blockIdx.x * blockDim.x + threadIdx.x;
    if (i >= 10 * NTOT) return;
    deg[i] = 1.0f;
    float x0 = feat[i * 2], x1 = feat[i * 2 + 1];
    xw[i * 2]     = x0 * wg[0] + x1 * wg[1];
    xw[i * 2 + 1] = x0 * wg[2] + x1 * wg[3];
}

__global__ void bgcn_count(const int* __restrict__ ei, float* __restrict__ deg) {
    int e = blockIdx.x * blockDim.x + threadIdx.x;
    if (e >= 10 * NEDGE) return;
    int t = e >> 16, el = e & 65535;
    int dst = ei[t * 2 * NEDGE + NEDGE + el];
    atomicAdd(&deg[t * NTOT + dst], 1.0f);
}

__global__ void bgcn_node(const float* __restrict__ bg, float* __restrict__ deg,
                          const float* __restrict__ xw, float* __restrict__ gT_all) {
    int i = blockIdx.x * blockDim.x + threadIdx.x;
    if (i >= 10 * NTOT) return;
    float dinv = rsqrtf(deg[i]);
    deg[i] = dinv;
    int t = i >> 12, node = i & 4095;
    int b = node >> 6, nn = node & 63;
    float w2 = dinv * dinv;
    gT_all[t * 8192 + (nn * 2 + 0) * 64 + b] = xw[i * 2]     * w2 + bg[0];
    gT_all[t * 8192 + (nn * 2 + 1) * 64 + b] = xw[i * 2 + 1] * w2 + bg[1];
}

// LDS-accumulated edge scatter: 8 blocks per frame
__global__ __launch_bounds__(256) void bgcn_scatter_lds(const int* __restrict__ ei,
                                                        const float* __restrict__ dinv,
                                                        const float* __restrict__ xw,
                                                        float* __restrict__ gT_all) {
    __shared__ float sg[8192];
    int t = blockIdx.x >> 3;
    int chunk = blockIdx.x & 7;
    for (int i = threadIdx.x; i < 8192; i += 256) sg[i] = 0.f;
    __syncthreads();
    const int* eis = ei + t * 2 * NEDGE;
    int e0 = chunk * 8192;
    for (int e = e0 + threadIdx.x; e < e0 + 8192; e += 256) {
        int s = eis[e];
        int d = eis[NEDGE + e];
        float w = dinv[t * NTOT + s] * dinv[t * NTOT + d];
        int b = d >> 6, nn = d & 63;
        atomicAdd(&sg[(nn * 2 + 0) * 64 + b], xw[(t * NTOT + s) * 2]     * w);
        atomicAdd(&sg[(nn * 2 + 1) * 64 + b], xw[(t * NTOT + s) * 2 + 1] * w);
    }
    __syncthreads();
    float* gt = gT_all + t * 8192;
    for (int i = threadIdx.x; i < 8192; i += 256) {
        float v = sg[i];
        if (v != 0.f) atomicAdd(&gt[i], v);
    }
}

// ==================== broadcast-x GEMM v7: bx3 inner loop, 32-wide n-tile, STG=64 ====================
// P[ks][n][m] = sum over k-chunk ks of in[m][k] * W[n][k].
// thread: ns = tid>>3 (n within 32-tile), q = tid&7 -> m in [q*8, q*8+8).
// 16KB LDS + doubled grid -> 4+ blocks/CU (vs bx3's 2) to hide W-load latency.
template<int KC>
__global__ __launch_bounds__(256) void gemm_bx7(
    const float* __restrict__ inT, const float* __restrict__ inT2,
    const float* __restrict__ WT,  const float* __restrict__ WT2,
    float* __restrict__ P, int NO, int SK1)
{
    constexpr int STG = (KC > 64) ? 64 : KC;
    __shared__ float xs[STG * 64];   // <=16KB
    int tid = threadIdx.x;
    int ks = blockIdx.y;
    const float* xsrc; const float* wsrc;
    if (ks < SK1) { xsrc = inT  + (size_t)ks * KC * 64;         wsrc = WT  + (size_t)ks * KC * NO; }
    else          { xsrc = inT2 + (size_t)(ks - SK1) * KC * 64; wsrc = WT2 + (size_t)(ks - SK1) * KC * NO; }
    int ns = tid >> 3, q = tid & 7;
    int n = blockIdx.x * 32 + ns;
    const float* xq = xs + q * 8;
    float acc[8];
    #pragma unroll
    for (int j = 0; j < 8; ++j) acc[j] = 0.f;

    for (int kb = 0; kb < KC; kb += STG) {
        if (kb) __syncthreads();
        #pragma unroll
        for (int i = 0; i < STG / 16; ++i)
            ((float4*)xs)[tid + i * 256] = ((const float4*)(xsrc + (size_t)kb * 64))[tid + i * 256];
        __syncthreads();
        const float* wp = wsrc + (size_t)kb * NO + n;
        float wbuf[4];
        #pragma unroll
        for (int kk = 0; kk < 4; ++kk) wbuf[kk] = wp[(size_t)kk * NO];
        for (int k = 0; k < STG; k += 4) {
            float wn[4] = {0.f, 0.f, 0.f, 0.f};
            if (k + 4 < STG) {
                #pragma unroll
                for (int kk = 0; kk < 4; ++kk) wn[kk] = wp[(size_t)(k + 4 + kk) * NO];
            }
            #pragma unroll
            for (int kk = 0; kk < 4; ++kk) {
                const float* xrow = xq + (k + kk) * 64;
                float w = wbuf[kk];
                float4 x0 = *(const float4*)(xrow + 0);
                float4 x1 = *(const float4*)(xrow + 4);
                acc[0] = fmaf(w, x0.x, acc[0]);  acc[1] = fmaf(w, x0.y, acc[1]);
                acc[2] = fmaf(w, x0.z, acc[2]);  acc[3] = fmaf(w, x0.w, acc[3]);
                acc[4] = fmaf(w, x1.x, acc[4]);  acc[5] = fmaf(w, x1.y, acc[5]);
                acc[6] = fmaf(w, x1.z, acc[6]);  acc[7] = fmaf(w, x1.w, acc[7]);
            }
            #pragma unroll
            for (int kk = 0; kk < 4; ++kk) wbuf[kk] = wn[kk];
        }
    }
    float* pp = P + ((size_t)ks * NO + n) * 64 + q * 8;
    *(float4*)(pp + 0) = make_float4(acc[0], acc[1], acc[2], acc[3]);
    *(float4*)(pp + 4) = make_float4(acc[4], acc[5], acc[6], acc[7]);
}

// ==================== reduce partials + bias (+relu) -> aT (NO,64) ====================
__global__ void reduce_relu_kernel(const float* __restrict__ P,
                                   const float* __restrict__ bias,
                                   float* __restrict__ aT,
                                   int NO, int SK, int relu) {
    int idx = blockIdx.x * blockDim.x + threadIdx.x;
    if (idx >= NO * 64) return;
    int n = idx >> 6;
    float v = bias[n];
    for (int ks = 0; ks < SK; ++ks) v += P[(size_t)ks * NO * 64 + idx];
    if (relu) v = fmaxf(v, 0.f);
    aT[idx] = v;
}

// ==================== LSTM pointwise from 9 partials (+ optional bf16 h-stash) ====================
__global__ void lstm_update2(const float* __restrict__ P,
                             const float* __restrict__ b_ih, const float* __restrict__ b_hh,
                             float* __restrict__ hT, float* __restrict__ cT,
                             unsigned short* __restrict__ stash, int mbase) {
    int t = blockIdx.x * blockDim.x + threadIdx.x;
    if (t >= HDIM * BSZ) return;
    int j = t >> 6, b = t & 63;
    float g4[4];
    #pragma unroll
    for (int gi = 0; gi < 4; ++gi) {
        int row = gi * HDIM + j;
        float v = b_ih[row] + b_hh[row];
        size_t base = (size_t)row * 64 + b;
        #pragma unroll
        for (int ks = 0; ks < 9; ++ks) v += P[(size_t)ks * 4096 * 64 + base];
        g4[gi] = v;
    }
    float si = 1.f / (1.f + expf(-g4[0]));
    float sf = 1.f / (1.f + expf(-g4[1]));
    float gg = tanhf(g4[2]);
    float so = 1.f / (1.f + expf(-g4[3]));
    float cn = sf * cT[t] + si * gg;
    cT[t] = cn;
    float h = so * tanhf(cn);
    hT[t] = h;
    if (stash) stash[(size_t)(mbase + b) * HDIM + j] = f2bf(h);
}

// ==================== finalize3: reduce l5 partials + l6 GEMM + frame (+adj + dense GCN) ====================
// P: l5 partials (16, 512, 64). wt5: (512,128) = l6 W^T. block = trajectory, 128 threads.
__global__ void finalize3(const float* __restrict__ P, const float* __restrict__ b5,
                          const float* __restrict__ wt5, const float* __restrict__ b6,
                          const float* __restrict__ stats, const float* __restrict__ wg,
                          const float* __restrict__ bg,
                          float* __restrict__ frame, float* __restrict__ gT, int dec)
{
    int b = blockIdx.x;
    int n = threadIdx.x;   // 0..127
    __shared__ float a5[512];
    __shared__ float p[128];
    __shared__ float f0[NN], f1[NN], sxw0[NN], sxw1[NN], sdinv[NN];
    __shared__ int ex[NN];
    #pragma unroll
    for (int j = 0; j < 4; ++j) {
        int k = n * 4 + j;
        float v = b5[k];
        #pragma unroll 4
        for (int ks = 0; ks < 16; ++ks) v += P[((size_t)ks * 512 + k) * 64 + b];
        a5[k] = fmaxf(v, 0.f);
    }
    __syncthreads();
    float acc = b6[n];
    for (int k = 0; k < 512; ++k) acc = fmaf(a5[k], wt5[k * 128 + n], acc);
    p[n] = acc;
    frame[b * 128 + n] = acc;
    if (!dec) return;
    __syncthreads();
    int i = n;
    if (i < NN) {
        float p0 = p[i * 2], p1 = p[i * 2 + 1];
        float d0 = p0 * stats[0] + stats[2];
        float d1 = p1 * stats[1] + stats[3];
        f0[i] = d0; f1[i] = d1;
        ex[i] = (d0 > 0.04f) && (d1 > 0.04f);
        sxw0[i] = p0 * wg[0] + p1 * wg[1];
        sxw1[i] = p0 * wg[2] + p1 * wg[3];
    }
    __syncthreads();
    if (i < NN) {
        float fi0 = f0[i], fi1 = f1[i];
        int exi = ex[i];
        float deg = 0.f;
        for (int j = 0; j < NN; ++j) {
            float dx = fi0 - f0[j], dy = fi1 - f1[j];
            float a = (i == j) ? 1.0f :
                      ((dx * dx + dy * dy <= 100.0f && exi && ex[j]) ? 1.0f : 0.0f);
            deg += a;
        }
        sdinv[i] = rsqrtf(deg);
    }
    __syncthreads();
    if (i < NN) {
        float fi0 = f0[i], fi1 = f1[i];
        int exi = ex[i];
        float a0 = 0.f, a1 = 0.f;
        for (int j = 0; j < NN; ++j) {
            float dx = fi0 - f0[j], dy = fi1 - f1[j];
            float a = (i == j) ? 1.0f :
                      ((dx * dx + dy * dy <= 100.0f && exi && ex[j]) ? 1.0f : 0.0f);
            float an = a * sdinv[j];
            a0 += an * sxw0[j];
            a1 += an * sxw1[j];
        }
        float di = sdinv[i];
        gT[(i * 2 + 0) * 64 + b] = a0 * di + bg[0];
        gT[(i * 2 + 1) * 64 + b] = a1 * di + bg[1];
    }
}

// ==================== combined bf16 pack (task list) ====================
struct PTasks {
    const float* W[6]; unsigned short* Bp[6]; int K[6]; int goff[7];
};
__global__ void pack_all(PTasks pt) {
    int g = blockIdx.x * blockDim.x + threadIdx.x;
    if (g >= pt.goff[6]) return;
    int l = 0;
    #pragma unroll
    for (int j = 1; j < 6; ++j) if (g >= pt.goff[j]) l = j;
    int local = g - pt.goff[l];
    int kgs = pt.K[l] >> 3;
    int kg = local % kgs;
    int n  = local / kgs;
    const float* src = pt.W[l] + (size_t)n * pt.K[l] + (size_t)kg * 8;
    unsigned short* dst = pt.Bp[l] + ((size_t)kg * (pt.goff[l + 1] - pt.goff[l]) / kgs + n) * 8;
    #pragma unroll
    for (int j = 0; j < 8; ++j) dst[j] = f2bf(src[j]);
}

// ==================== batched MFMA MLP layer v2 + split-K (blockIdx.z) ====================
__global__ __launch_bounds__(256) void gemm_mfma2(
    const unsigned short* __restrict__ inb,
    const unsigned short* __restrict__ Bp,
    const float* __restrict__ bias,
    unsigned short* __restrict__ outb,
    float* __restrict__ frames,
    float* __restrict__ accbuf,
    int K, int KC, int NO, int relu)
{
    __shared__ unsigned short A[64][72];
    int tid = threadIdx.x;
    int lane = tid & 63;
    int w = tid >> 6;
    int m0 = blockIdx.y * 64;
    int nb = blockIdx.x * 64;
    int koff = blockIdx.z * KC;
    int l15 = lane & 15;
    int lq  = lane >> 4;
    int n = nb + w * 16 + l15;
    int sm = tid >> 3, skq = tid & 7;
    const unsigned short* bpb = Bp + (size_t)(koff >> 3) * NO * 8;
    f32x4 acc[4] = {};

    {
        s16x8 a0 = *(const s16x8*)&inb[(size_t)(m0 + sm) * K + koff + skq * 8];
        s16x8 a1 = *(const s16x8*)&inb[(size_t)(m0 + sm + 32) * K + koff + skq * 8];
        *(s16x8*)&A[sm][skq * 8] = a0;
        *(s16x8*)&A[sm + 32][skq * 8] = a1;
    }
    __syncthreads();
    s16x8 b0 = *(const s16x8*)&bpb[((size_t)(0 + lq) * NO + n) * 8];
    s16x8 b1 = *(const s16x8*)&bpb[((size_t)(4 + lq) * NO + n) * 8];

    int nk = KC >> 6;
    for (int t = 0; t < nk; ++t) {
        s16x8 na0, na1, nb0, nb1;
        bool more = (t + 1 < nk);
        if (more) {
            int ko = koff + (t + 1) * 64;
            na0 = *(const s16x8*)&inb[(size_t)(m0 + sm) * K + ko + skq * 8];
            na1 = *(const s16x8*)&inb[(size_t)(m0 + sm + 32) * K + ko + skq * 8];
            int kg = (t + 1) * 8;
            nb0 = *(const s16x8*)&bpb[((size_t)(kg + lq) * NO + n) * 8];
            nb1 = *(const s16x8*)&bpb[((size_t)(kg + 4 + lq) * NO + n) * 8];
        }
        #pragma unroll
        for (int s = 0; s < 4; ++s) {
            s16x8 af = *(const s16x8*)&A[s * 16 + l15][lq * 8];
            acc[s] = __builtin_amdgcn_mfma_f32_16x16x32_bf16(af, b0, acc[s], 0, 0, 0);
        }
        #pragma unroll
        for (int s = 0; s < 4; ++s) {
            s16x8 af = *(const s16x8*)&A[s * 16 + l15][32 + lq * 8];
            acc[s] = __builtin_amdgcn_mfma_f32_16x16x32_bf16(af, b1, acc[s], 0, 0, 0);
        }
        if (more) {
            __syncthreads();
            *(s16x8*)&A[sm][skq * 8] = na0;
            *(s16x8*)&A[sm + 32][skq * 8] = na1;
            __syncthreads();
            b0 = nb0; b1 = nb1;
        }
    }
    if (accbuf) {
        #pragma unroll
        for (int s = 0; s < 4; ++s) {
            #pragma unroll
            for (int r = 0; r < 4; ++r) {
                int m = m0 + s * 16 + lq * 4 + r;
                atomicAdd(&accbuf[(size_t)m * NO + n], acc[s][r]);
            }
        }
        return;
    }
    float bn = bias[n];
    #pragma unroll
    for (int s = 0; s < 4; ++s) {
        #pragma unroll
        for (int r = 0; r < 4; ++r) {
            int m = m0 + s * 16 + lq * 4 + r;
            float v = acc[s][r] + bn;
            if (relu) v = fmaxf(v, 0.f);
            if (outb) outb[(size_t)m * NO + n] = f2bf(v);
            if (frames && m < 576) {
                int f = m >> 6, b = m & 63;
                frames[(size_t)f * FRAME_ELEMS + b * 128 + n] = v;
            }
        }
    }
}

// ==================== bias+relu+pack for split-K accumulated layers ====================
__global__ void packrelu_kernel(const float* __restrict__ acc, const float* __restrict__ bias,
                                unsigned short* __restrict__ outb, int NO) {
    int idx = blockIdx.x * blockDim.x + threadIdx.x;
    if (idx >= 576 * NO) return;
    int n = idx & (NO - 1);   // NO is a power of 2
    float v = acc[idx] + bias[n];
    outb[idx] = f2bf(fmaxf(v, 0.f));
}

// ==================== host ====================

extern "C" void kernel_launch(void* const* d_in, const int* in_sizes, int n_in,
                              void* d_out, int out_size, void* d_ws, size_t ws_size,
                              hipStream_t stream) {
    const float* feat   = (const float*)d_in[0];
    const int*   ei_in  = (const int*)d_in[1];
    const float* stats  = (const float*)d_in[4];
    const float* w_gcn  = (const float*)d_in[5];
    const float* b_gcn  = (const float*)d_in[6];
    const float* w_ih   = (const float*)d_in[7];
    const float* w_hh   = (const float*)d_in[8];
    const float* b_ih   = (const float*)d_in[9];
    const float* b_hh   = (const float*)d_in[10];
    const float* wm[6], *bm[6];
    for (int i = 0; i < 6; ++i) { wm[i] = (const float*)d_in[11 + 2*i]; bm[i] = (const float*)d_in[12 + 2*i]; }
    const int mlp_K[6]  = {1024, 2048, 4096, 2048, 1024, 512};
    const int mlp_NO[6] = {2048, 4096, 2048, 1024, 512, 128};

    float* out = (float*)d_out;
    float* ws  = (float*)d_ws;

    // ---------- workspace layout (floats) ----------
    size_t off = 0;
    float* wt_ih = ws + off; off += (size_t)128 * 4096;
    float* wt_hh = ws + off; off += (size_t)1024 * 4096;
    float* wt[6];
    const size_t wt_sz[6] = {(size_t)1024*2048, (size_t)2048*4096, (size_t)4096*2048,
                             (size_t)2048*1024, (size_t)1024*512, (size_t)512*128};
    for (int i = 0; i < 6; ++i) { wt[i] = ws + off; off += wt_sz[i]; }
    float* P      = ws + off; off += (size_t)32 * 2048 * 64;  // 4.19M floats
    float* gT_all = ws + off; off += (size_t)10 * 128 * 64;
    float* gT_dec = ws + off; off += 8192;
    float* hT     = ws + off; off += 65536;
    float* cT     = ws + off; off += 65536;
    float* aT1    = ws + off; off += 131072;
    float* aT2    = ws + off; off += 262144;
    float* aT3    = aT1;       // aliases: aT1 dead after l2 stage reads it
    float* aT4    = aT2;       // aliases: aT2 dead after l3 stage reads it
    float* inb1f  = ws + off; off += 147456;                  // 576*1024 bf16 (overlaps deg/xw)
    float* deg    = inb1f;                                    // 40960 floats, dead before inb1 written
    float* xw     = inb1f + 40960;                            // 81920 floats, ditto
    size_t need_bytes = off * sizeof(float);
    if (ws_size < need_bytes) return;

    // bf16 views: inb2..6 alias P (dead during final MFMA phase); 11.2MB <= 16.8MB
    unsigned short* inb1 = (unsigned short*)inb1f;
    unsigned short* inb2 = (unsigned short*)P;
    unsigned short* inb3 = inb2 + (size_t)576 * 2048;
    unsigned short* inb4 = inb3 + (size_t)576 * 4096;
    unsigned short* inb5 = inb4 + (size_t)576 * 2048;
    unsigned short* inb6 = inb5 + (size_t)576 * 1024;
    unsigned short* Bp[6];
    {
        unsigned short* base = (unsigned short*)wt[0];
        size_t boff = 0;
        for (int l = 0; l < 6; ++l) { Bp[l] = base + boff; boff += (size_t)mlp_NO[l] * mlp_K[l]; }
    }
    // split-K fp32 accumulator aliases wt_hh (fp32 LSTM weights dead after step 14)
    float* accbuf = wt_hh;   // 4.19M floats >= 576*4096

    hipMemsetAsync(hT, 0, 2 * 65536 * sizeof(float), stream);
    hipMemcpyAsync(out, feat, FRAME_ELEMS * sizeof(float), hipMemcpyDeviceToDevice, stream);

    // ---------- upfront: all weight transposes in one launch ----------
    {
        TT8 tasks;
        const float* Wp[8] = {w_ih, w_hh, wm[0], wm[1], wm[2], wm[3], wm[4], wm[5]};
        float* WTp[8] = {wt_ih, wt_hh, wt[0], wt[1], wt[2], wt[3], wt[4], wt[5]};
        int NOs[8] = {4096, 4096, 2048, 4096, 2048, 1024, 512, 128};
        int Ks[8]  = {128, 1024, 1024, 2048, 4096, 2048, 1024, 512};
        int toff = 0;
        for (int j = 0; j < 8; ++j) {
            tasks.t[j] = {Wp[j], WTp[j], NOs[j], Ks[j], toff};
            toff += (Ks[j] >> 5) * (NOs[j] >> 5);
        }
        transpose_all<<<toff, 256, 0, stream>>>(tasks);
    }

    // ---------- upfront: batched GCN for all 10 input frames ----------
    bgcn_init_xw<<<10 * NTOT / 256, 256, 0, stream>>>(feat, w_gcn, deg, xw);
    bgcn_count<<<10 * NEDGE / 256, 256, 0, stream>>>(ei_in, deg);
    bgcn_node<<<10 * NTOT / 256, 256, 0, stream>>>(b_gcn, deg, xw, gT_all);
    bgcn_scatter_lds<<<80, 256, 0, stream>>>(ei_in, deg, xw, gT_all);

    // ---------- 15 serial steps ----------
    for (int s = 0; s < 15; ++s) {
        const float* gT_s = (s <= 9) ? (gT_all + (size_t)s * 8192) : gT_dec;

        // LSTM: ks 0..7 = hh chunks (K=1024, KC=128), ks 8 = ih (K=128)
        gemm_bx7<128><<<dim3(128, 9), 256, 0, stream>>>(hT, gT_s, wt_hh, wt_ih, P, 4096, 8);
        lstm_update2<<<HDIM * BSZ / 256, 256, 0, stream>>>(
            P, b_ih, b_hh, hT, cT, (s <= 8) ? inb1 : nullptr, s * 64);

        if (s >= 9) {
            float* frame = out + (size_t)(s + 1) * FRAME_ELEMS;
            // l1: K=1024 NO=2048 KC=64 SK=16
            gemm_bx7<64><<<dim3(64, 16), 256, 0, stream>>>(hT, nullptr, wt[0], nullptr, P, 2048, 16);
            reduce_relu_kernel<<<2048 * 64 / 256, 256, 0, stream>>>(P, bm[0], aT1, 2048, 16, 1);
            // l2: K=2048 NO=4096 KC=256 (staged 4x64) SK=8
            gemm_bx7<256><<<dim3(128, 8), 256, 0, stream>>>(aT1, nullptr, wt[1], nullptr, P, 4096, 8);
            reduce_relu_kernel<<<4096 * 64 / 256, 256, 0, stream>>>(P, bm[1], aT2, 4096, 8, 1);
            // l3: K=4096 NO=2048 KC=256 (staged 4x64) SK=16
            gemm_bx7<256><<<dim3(64, 16), 256, 0, stream>>>(aT2, nullptr, wt[2], nullptr, P, 2048, 16);
            reduce_relu_kernel<<<2048 * 64 / 256, 256, 0, stream>>>(P, bm[2], aT3, 2048, 16, 1);
            // l4: K=2048 NO=1024 KC=128 SK=16
            gemm_bx7<128><<<dim3(32, 16), 256, 0, stream>>>(aT3, nullptr, wt[3], nullptr, P, 1024, 16);
            reduce_relu_kernel<<<1024 * 64 / 256, 256, 0, stream>>>(P, bm[3], aT4, 1024, 16, 1);
            // l5: K=1024 NO=512 KC=64 SK=16 (partials only; finalize3 reduces)
            gemm_bx7<64><<<dim3(16, 16), 256, 0, stream>>>(aT4, nullptr, wt[4], nullptr, P, 512, 16);
            // finalize: reduce l5 + l6 GEMM + frame write (+ adjacency + dense GCN)
            finalize3<<<BSZ, 128, 0, stream>>>(P, bm[4], wt[5], bm[5], stats, w_gcn, b_gcn,
                                               frame, gT_dec, (s < 14) ? 1 : 0);
        }
    }

    // ---------- batched encoder MLP (frames 1..9), bf16 MFMA, M=576, split-K ----------
    {
        PTasks pt;
        int goff = 0;
        for (int l = 0; l < 6; ++l) {
            pt.W[l] = wm[l]; pt.Bp[l] = Bp[l]; pt.K[l] = mlp_K[l];
            pt.goff[l] = goff;
            goff += mlp_NO[l] * (mlp_K[l] >> 3);
        }
        pt.goff[6] = goff;
        pack_all<<<(goff + 255) / 256, 256, 0, stream>>>(pt);
    }
    unsigned short* chain_in[6]  = {inb1, inb2, inb3, inb4, inb5, inb6};
    unsigned short* chain_out[6] = {inb2, inb3, inb4, inb5, inb6, nullptr};
    const int mlp_SK[6] = {2, 4, 8, 4, 2, 1};   // KC = K/SK = 512 everywhere
    for (int l = 0; l < 6; ++l) {
        int NO = mlp_NO[l], K = mlp_K[l], SK = mlp_SK[l], KC = K / SK;
        if (l < 5) {
            hipMemsetAsync(accbuf, 0, (size_t)576 * NO * sizeof(float), stream);
            gemm_mfma2<<<dim3(NO / 64, 9, SK), 256, 0, stream>>>(
                chain_in[l], Bp[l], bm[l], nullptr, nullptr, accbuf, K, KC, NO, 0);
            packrelu_kernel<<<(576 * NO + 255) / 256, 256, 0, stream>>>(
                accbuf, bm[l], chain_out[l], NO);
        } else {
            gemm_mfma2<<<dim3(NO / 64, 9, 1), 256, 0, stream>>>(
                chain_in[l], Bp[l], bm[l], nullptr, out + FRAME_ELEMS, nullptr, K, KC, NO, 0);
        }
    }
}

// Round 14
// 1325.713 us; speedup vs baseline: 1.2725x; 1.2030x over previous
//
#include <hip/hip_runtime.h>
#include <hip/hip_bf16.h>
#include <math.h>

// Problem constants
#define NTOT 4096      // B*N nodes
#define NEDGE 65536    // E edges
#define BSZ 64         // batch
#define NN 64          // nodes per trajectory
#define HDIM 1024      // LSTM hidden
#define TIN 10
#define TOUT 6
#define FRAME_ELEMS (NTOT * 2)   // 8192 floats per frame

typedef short s16x8 __attribute__((ext_vector_type(8)));
typedef float f32x4 __attribute__((ext_vector_type(4)));

__device__ __forceinline__ unsigned short f2bf(float f) {
    union { float f; unsigned u; } x; x.f = f;
    unsigned r = x.u + 0x7fffu + ((x.u >> 16) & 1u);
    return (unsigned short)(r >> 16);
}

// ==================== weight transpose (task list; now only used for wm[5]) ====================
struct TT { const float* W; float* WT; int NO; int K; int toff; };
struct TT8 { TT t[8]; };

__global__ __launch_bounds__(256) void transpose_all(TT8 tasks) {
    int bid = blockIdx.x;
    int ti = 0;
    #pragma unroll
    for (int j = 1; j < 8; ++j) if (bid >= tasks.t[j].toff) ti = j;
    TT tk = tasks.t[ti];
    int local = bid - tk.toff;
    int tilesK = tk.K >> 5;
    int kb = local % tilesK, nb = local / tilesK;
    int k0 = kb * 32, n0 = nb * 32;
    __shared__ float t[32][33];
    int tx = threadIdx.x & 31, ty = threadIdx.x >> 5;  // 32 x 8
    #pragma unroll
    for (int i = 0; i < 4; ++i)
        t[ty + i * 8][tx] = tk.W[(size_t)(n0 + ty + i * 8) * tk.K + k0 + tx];
    __syncthreads();
    #pragma unroll
    for (int i = 0; i < 4; ++i)
        tk.WT[(size_t)(k0 + ty + i * 8) * tk.NO + n0 + tx] = t[tx][ty + i * 8];
}

// ==================== batched GCN over 10 input frames ====================

__global__ void bgcn_init_xw(const float* __restrict__ feat, const float* __restrict__ wg,
                             float* __restrict__ deg, float* __restrict__ xw) {
    int i = blockIdx.x * blockDim.x + threadIdx.x;
    if (i >= 10 * NTOT) return;
    deg[i] = 1.0f;
    float x0 = feat[i * 2], x1 = feat[i * 2 + 1];
    xw[i * 2]     = x0 * wg[0] + x1 * wg[1];
    xw[i * 2 + 1] = x0 * wg[2] + x1 * wg[3];
}

__global__ void bgcn_count(const int* __restrict__ ei, float* __restrict__ deg) {
    int e = blockIdx.x * blockDim.x + threadIdx.x;
    if (e >= 10 * NEDGE) return;
    int t = e >> 16, el = e & 65535;
    int dst = ei[t * 2 * NEDGE + NEDGE + el];
    atomicAdd(&deg[t * NTOT + dst], 1.0f);
}

__global__ void bgcn_node(const float* __restrict__ bg, float* __restrict__ deg,
                          const float* __restrict__ xw, float* __restrict__ gT_all) {
    int i = blockIdx.x * blockDim.x + threadIdx.x;
    if (i >= 10 * NTOT) return;
    float dinv = rsqrtf(deg[i]);
    deg[i] = dinv;
    int t = i >> 12, node = i & 4095;
    int b = node >> 6, nn = node & 63;
    float w2 = dinv * dinv;
    gT_all[t * 8192 + (nn * 2 + 0) * 64 + b] = xw[i * 2]     * w2 + bg[0];
    gT_all[t * 8192 + (nn * 2 + 1) * 64 + b] = xw[i * 2 + 1] * w2 + bg[1];
}

// LDS-accumulated edge scatter: 8 blocks per frame
__global__ __launch_bounds__(256) void bgcn_scatter_lds(const int* __restrict__ ei,
                                                        const float* __restrict__ dinv,
                                                        const float* __restrict__ xw,
                                                        float* __restrict__ gT_all) {
    __shared__ float sg[8192];
    int t = blockIdx.x >> 3;
    int chunk = blockIdx.x & 7;
    for (int i = threadIdx.x; i < 8192; i += 256) sg[i] = 0.f;
    __syncthreads();
    const int* eis = ei + t * 2 * NEDGE;
    int e0 = chunk * 8192;
    for (int e = e0 + threadIdx.x; e < e0 + 8192; e += 256) {
        int s = eis[e];
        int d = eis[NEDGE + e];
        float w = dinv[t * NTOT + s] * dinv[t * NTOT + d];
        int b = d >> 6, nn = d & 63;
        atomicAdd(&sg[(nn * 2 + 0) * 64 + b], xw[(t * NTOT + s) * 2]     * w);
        atomicAdd(&sg[(nn * 2 + 1) * 64 + b], xw[(t * NTOT + s) * 2 + 1] * w);
    }
    __syncthreads();
    float* gt = gT_all + t * 8192;
    for (int i = threadIdx.x; i < 8192; i += 256) {
        float v = sg[i];
        if (v != 0.f) atomicAdd(&gt[i], v);
    }
}

// ==================== broadcast-x GEMM v8: bx7 tile, ROW-MAJOR W (no transpose needed) ====================
// P[ks][n][m] = sum over k-chunk ks of in[m][k] * W[n][k], W row-major (NO, strideW).
// thread: ns = tid>>3 (n within 32-tile), q = tid&7 -> m in [q*8, q*8+8).
// Wave has only 8 distinct n (8-fold q redundancy) -> W float4 loads cost 128B/wave per 4k,
// same bytes as the transposed path, 4x fewer load instructions.
template<int KC>
__global__ __launch_bounds__(256) void gemm_bx8(
    const float* __restrict__ inT, const float* __restrict__ inT2,
    const float* __restrict__ W1,  const float* __restrict__ W2,
    int st1, int st2,
    float* __restrict__ P, int NO, int SK1)
{
    constexpr int STG = (KC > 64) ? 64 : KC;
    __shared__ float xs[STG * 64];   // <=16KB
    int tid = threadIdx.x;
    int ks = blockIdx.y;
    const float* xsrc; const float* wrow; int koff, strideW;
    if (ks < SK1) { xsrc = inT  + (size_t)ks * KC * 64;         wrow = W1; koff = ks * KC;         strideW = st1; }
    else          { xsrc = inT2 + (size_t)(ks - SK1) * KC * 64; wrow = W2; koff = (ks - SK1) * KC; strideW = st2; }
    int ns = tid >> 3, q = tid & 7;
    int n = blockIdx.x * 32 + ns;
    const float* wp0 = wrow + (size_t)n * strideW + koff;
    const float* xq = xs + q * 8;
    float acc[8];
    #pragma unroll
    for (int j = 0; j < 8; ++j) acc[j] = 0.f;

    for (int kb = 0; kb < KC; kb += STG) {
        if (kb) __syncthreads();
        #pragma unroll
        for (int i = 0; i < STG / 16; ++i)
            ((float4*)xs)[tid + i * 256] = ((const float4*)(xsrc + (size_t)kb * 64))[tid + i * 256];
        __syncthreads();
        const float* wp = wp0 + kb;
        float4 wA = *(const float4*)(wp + 0);
        float4 wB = *(const float4*)(wp + 4);
        for (int k = 0; k < STG; k += 8) {
            float4 wC, wD;
            if (k + 8 < STG)  wC = *(const float4*)(wp + k + 8);
            if (k + 12 < STG) wD = *(const float4*)(wp + k + 12);
            // consume wA: k .. k+3
            #pragma unroll
            for (int kk = 0; kk < 4; ++kk) {
                const float* xrow = xq + (k + kk) * 64;
                float w = (kk == 0) ? wA.x : (kk == 1) ? wA.y : (kk == 2) ? wA.z : wA.w;
                float4 x0 = *(const float4*)(xrow + 0);
                float4 x1 = *(const float4*)(xrow + 4);
                acc[0] = fmaf(w, x0.x, acc[0]);  acc[1] = fmaf(w, x0.y, acc[1]);
                acc[2] = fmaf(w, x0.z, acc[2]);  acc[3] = fmaf(w, x0.w, acc[3]);
                acc[4] = fmaf(w, x1.x, acc[4]);  acc[5] = fmaf(w, x1.y, acc[5]);
                acc[6] = fmaf(w, x1.z, acc[6]);  acc[7] = fmaf(w, x1.w, acc[7]);
            }
            // consume wB: k+4 .. k+7
            #pragma unroll
            for (int kk = 0; kk < 4; ++kk) {
                const float* xrow = xq + (k + 4 + kk) * 64;
                float w = (kk == 0) ? wB.x : (kk == 1) ? wB.y : (kk == 2) ? wB.z : wB.w;
                float4 x0 = *(const float4*)(xrow + 0);
                float4 x1 = *(const float4*)(xrow + 4);
                acc[0] = fmaf(w, x0.x, acc[0]);  acc[1] = fmaf(w, x0.y, acc[1]);
                acc[2] = fmaf(w, x0.z, acc[2]);  acc[3] = fmaf(w, x0.w, acc[3]);
                acc[4] = fmaf(w, x1.x, acc[4]);  acc[5] = fmaf(w, x1.y, acc[5]);
                acc[6] = fmaf(w, x1.z, acc[6]);  acc[7] = fmaf(w, x1.w, acc[7]);
            }
            wA = wC; wB = wD;
        }
    }
    float* pp = P + ((size_t)ks * NO + n) * 64 + q * 8;
    *(float4*)(pp + 0) = make_float4(acc[0], acc[1], acc[2], acc[3]);
    *(float4*)(pp + 4) = make_float4(acc[4], acc[5], acc[6], acc[7]);
}

// ==================== reduce partials + bias (+relu) -> aT (NO,64) ====================
__global__ void reduce_relu_kernel(const float* __restrict__ P,
                                   const float* __restrict__ bias,
                                   float* __restrict__ aT,
                                   int NO, int SK, int relu) {
    int idx = blockIdx.x * blockDim.x + threadIdx.x;
    if (idx >= NO * 64) return;
    int n = idx >> 6;
    float v = bias[n];
    for (int ks = 0; ks < SK; ++ks) v += P[(size_t)ks * NO * 64 + idx];
    if (relu) v = fmaxf(v, 0.f);
    aT[idx] = v;
}

// ==================== LSTM pointwise from 9 partials (+ optional bf16 h-stash) ====================
__global__ void lstm_update2(const float* __restrict__ P,
                             const float* __restrict__ b_ih, const float* __restrict__ b_hh,
                             float* __restrict__ hT, float* __restrict__ cT,
                             unsigned short* __restrict__ stash, int mbase) {
    int t = blockIdx.x * blockDim.x + threadIdx.x;
    if (t >= HDIM * BSZ) return;
    int j = t >> 6, b = t & 63;
    float g4[4];
    #pragma unroll
    for (int gi = 0; gi < 4; ++gi) {
        int row = gi * HDIM + j;
        float v = b_ih[row] + b_hh[row];
        size_t base = (size_t)row * 64 + b;
        #pragma unroll
        for (int ks = 0; ks < 9; ++ks) v += P[(size_t)ks * 4096 * 64 + base];
        g4[gi] = v;
    }
    float si = 1.f / (1.f + expf(-g4[0]));
    float sf = 1.f / (1.f + expf(-g4[1]));
    float gg = tanhf(g4[2]);
    float so = 1.f / (1.f + expf(-g4[3]));
    float cn = sf * cT[t] + si * gg;
    cT[t] = cn;
    float h = so * tanhf(cn);
    hT[t] = h;
    if (stash) stash[(size_t)(mbase + b) * HDIM + j] = f2bf(h);
}

// ==================== finalize3: reduce l5 partials + l6 GEMM + frame (+adj + dense GCN) ====================
// P: l5 partials (16, 512, 64). wt5: (512,128) = l6 W^T. block = trajectory, 128 threads.
__global__ void finalize3(const float* __restrict__ P, const float* __restrict__ b5,
                          const float* __restrict__ wt5, const float* __restrict__ b6,
                          const float* __restrict__ stats, const float* __restrict__ wg,
                          const float* __restrict__ bg,
                          float* __restrict__ frame, float* __restrict__ gT, int dec)
{
    int b = blockIdx.x;
    int n = threadIdx.x;   // 0..127
    __shared__ float a5[512];
    __shared__ float p[128];
    __shared__ float f0[NN], f1[NN], sxw0[NN], sxw1[NN], sdinv[NN];
    __shared__ int ex[NN];
    #pragma unroll
    for (int j = 0; j < 4; ++j) {
        int k = n * 4 + j;
        float v = b5[k];
        #pragma unroll 4
        for (int ks = 0; ks < 16; ++ks) v += P[((size_t)ks * 512 + k) * 64 + b];
        a5[k] = fmaxf(v, 0.f);
    }
    __syncthreads();
    float acc = b6[n];
    for (int k = 0; k < 512; ++k) acc = fmaf(a5[k], wt5[k * 128 + n], acc);
    p[n] = acc;
    frame[b * 128 + n] = acc;
    if (!dec) return;
    __syncthreads();
    int i = n;
    if (i < NN) {
        float p0 = p[i * 2], p1 = p[i * 2 + 1];
        float d0 = p0 * stats[0] + stats[2];
        float d1 = p1 * stats[1] + stats[3];
        f0[i] = d0; f1[i] = d1;
        ex[i] = (d0 > 0.04f) && (d1 > 0.04f);
        sxw0[i] = p0 * wg[0] + p1 * wg[1];
        sxw1[i] = p0 * wg[2] + p1 * wg[3];
    }
    __syncthreads();
    if (i < NN) {
        float fi0 = f0[i], fi1 = f1[i];
        int exi = ex[i];
        float deg = 0.f;
        for (int j = 0; j < NN; ++j) {
            float dx = fi0 - f0[j], dy = fi1 - f1[j];
            float a = (i == j) ? 1.0f :
                      ((dx * dx + dy * dy <= 100.0f && exi && ex[j]) ? 1.0f : 0.0f);
            deg += a;
        }
        sdinv[i] = rsqrtf(deg);
    }
    __syncthreads();
    if (i < NN) {
        float fi0 = f0[i], fi1 = f1[i];
        int exi = ex[i];
        float a0 = 0.f, a1 = 0.f;
        for (int j = 0; j < NN; ++j) {
            float dx = fi0 - f0[j], dy = fi1 - f1[j];
            float a = (i == j) ? 1.0f :
                      ((dx * dx + dy * dy <= 100.0f && exi && ex[j]) ? 1.0f : 0.0f);
            float an = a * sdinv[j];
            a0 += an * sxw0[j];
            a1 += an * sxw1[j];
        }
        float di = sdinv[i];
        gT[(i * 2 + 0) * 64 + b] = a0 * di + bg[0];
        gT[(i * 2 + 1) * 64 + b] = a1 * di + bg[1];
    }
}

// ==================== combined bf16 pack (task list) ====================
struct PTasks {
    const float* W[6]; unsigned short* Bp[6]; int K[6]; int goff[7];
};
__global__ void pack_all(PTasks pt) {
    int g = blockIdx.x * blockDim.x + threadIdx.x;
    if (g >= pt.goff[6]) return;
    int l = 0;
    #pragma unroll
    for (int j = 1; j < 6; ++j) if (g >= pt.goff[j]) l = j;
    int local = g - pt.goff[l];
    int kgs = pt.K[l] >> 3;
    int kg = local % kgs;
    int n  = local / kgs;
    const float* src = pt.W[l] + (size_t)n * pt.K[l] + (size_t)kg * 8;
    unsigned short* dst = pt.Bp[l] + ((size_t)kg * (pt.goff[l + 1] - pt.goff[l]) / kgs + n) * 8;
    #pragma unroll
    for (int j = 0; j < 8; ++j) dst[j] = f2bf(src[j]);
}

// ==================== batched MFMA MLP layer v2 + split-K (blockIdx.z) ====================
__global__ __launch_bounds__(256) void gemm_mfma2(
    const unsigned short* __restrict__ inb,
    const unsigned short* __restrict__ Bp,
    const float* __restrict__ bias,
    unsigned short* __restrict__ outb,
    float* __restrict__ frames,
    float* __restrict__ accbuf,
    int K, int KC, int NO, int relu)
{
    __shared__ unsigned short A[64][72];
    int tid = threadIdx.x;
    int lane = tid & 63;
    int w = tid >> 6;
    int m0 = blockIdx.y * 64;
    int nb = blockIdx.x * 64;
    int koff = blockIdx.z * KC;
    int l15 = lane & 15;
    int lq  = lane >> 4;
    int n = nb + w * 16 + l15;
    int sm = tid >> 3, skq = tid & 7;
    const unsigned short* bpb = Bp + (size_t)(koff >> 3) * NO * 8;
    f32x4 acc[4] = {};

    {
        s16x8 a0 = *(const s16x8*)&inb[(size_t)(m0 + sm) * K + koff + skq * 8];
        s16x8 a1 = *(const s16x8*)&inb[(size_t)(m0 + sm + 32) * K + koff + skq * 8];
        *(s16x8*)&A[sm][skq * 8] = a0;
        *(s16x8*)&A[sm + 32][skq * 8] = a1;
    }
    __syncthreads();
    s16x8 b0 = *(const s16x8*)&bpb[((size_t)(0 + lq) * NO + n) * 8];
    s16x8 b1 = *(const s16x8*)&bpb[((size_t)(4 + lq) * NO + n) * 8];

    int nk = KC >> 6;
    for (int t = 0; t < nk; ++t) {
        s16x8 na0, na1, nb0, nb1;
        bool more = (t + 1 < nk);
        if (more) {
            int ko = koff + (t + 1) * 64;
            na0 = *(const s16x8*)&inb[(size_t)(m0 + sm) * K + ko + skq * 8];
            na1 = *(const s16x8*)&inb[(size_t)(m0 + sm + 32) * K + ko + skq * 8];
            int kg = (t + 1) * 8;
            nb0 = *(const s16x8*)&bpb[((size_t)(kg + lq) * NO + n) * 8];
            nb1 = *(const s16x8*)&bpb[((size_t)(kg + 4 + lq) * NO + n) * 8];
        }
        #pragma unroll
        for (int s = 0; s < 4; ++s) {
            s16x8 af = *(const s16x8*)&A[s * 16 + l15][lq * 8];
            acc[s] = __builtin_amdgcn_mfma_f32_16x16x32_bf16(af, b0, acc[s], 0, 0, 0);
        }
        #pragma unroll
        for (int s = 0; s < 4; ++s) {
            s16x8 af = *(const s16x8*)&A[s * 16 + l15][32 + lq * 8];
            acc[s] = __builtin_amdgcn_mfma_f32_16x16x32_bf16(af, b1, acc[s], 0, 0, 0);
        }
        if (more) {
            __syncthreads();
            *(s16x8*)&A[sm][skq * 8] = na0;
            *(s16x8*)&A[sm + 32][skq * 8] = na1;
            __syncthreads();
            b0 = nb0; b1 = nb1;
        }
    }
    if (accbuf) {
        #pragma unroll
        for (int s = 0; s < 4; ++s) {
            #pragma unroll
            for (int r = 0; r < 4; ++r) {
                int m = m0 + s * 16 + lq * 4 + r;
                atomicAdd(&accbuf[(size_t)m * NO + n], acc[s][r]);
            }
        }
        return;
    }
    float bn = bias[n];
    #pragma unroll
    for (int s = 0; s < 4; ++s) {
        #pragma unroll
        for (int r = 0; r < 4; ++r) {
            int m = m0 + s * 16 + lq * 4 + r;
            float v = acc[s][r] + bn;
            if (relu) v = fmaxf(v, 0.f);
            if (outb) outb[(size_t)m * NO + n] = f2bf(v);
            if (frames && m < 576) {
                int f = m >> 6, b = m & 63;
                frames[(size_t)f * FRAME_ELEMS + b * 128 + n] = v;
            }
        }
    }
}

// ==================== bias+relu+pack for split-K accumulated layers ====================
__global__ void packrelu_kernel(const float* __restrict__ acc, const float* __restrict__ bias,
                                unsigned short* __restrict__ outb, int NO) {
    int idx = blockIdx.x * blockDim.x + threadIdx.x;
    if (idx >= 576 * NO) return;
    int n = idx & (NO - 1);   // NO is a power of 2
    float v = acc[idx] + bias[n];
    outb[idx] = f2bf(fmaxf(v, 0.f));
}

// ==================== host ====================

extern "C" void kernel_launch(void* const* d_in, const int* in_sizes, int n_in,
                              void* d_out, int out_size, void* d_ws, size_t ws_size,
                              hipStream_t stream) {
    const float* feat   = (const float*)d_in[0];
    const int*   ei_in  = (const int*)d_in[1];
    const float* stats  = (const float*)d_in[4];
    const float* w_gcn  = (const float*)d_in[5];
    const float* b_gcn  = (const float*)d_in[6];
    const float* w_ih   = (const float*)d_in[7];
    const float* w_hh   = (const float*)d_in[8];
    const float* b_ih   = (const float*)d_in[9];
    const float* b_hh   = (const float*)d_in[10];
    const float* wm[6], *bm[6];
    for (int i = 0; i < 6; ++i) { wm[i] = (const float*)d_in[11 + 2*i]; bm[i] = (const float*)d_in[12 + 2*i]; }
    const int mlp_K[6]  = {1024, 2048, 4096, 2048, 1024, 512};
    const int mlp_NO[6] = {2048, 4096, 2048, 1024, 512, 128};

    float* out = (float*)d_out;
    float* ws  = (float*)d_ws;

    // ---------- workspace layout (floats) — identical offsets to round 13 ----------
    size_t off = 0;
    float* wt_ih = ws + off; off += (size_t)128 * 4096;        // now unused scratch
    float* wt_hh = ws + off; off += (size_t)1024 * 4096;       // accbuf aliases this
    float* wt[6];
    const size_t wt_sz[6] = {(size_t)1024*2048, (size_t)2048*4096, (size_t)4096*2048,
                             (size_t)2048*1024, (size_t)1024*512, (size_t)512*128};
    for (int i = 0; i < 6; ++i) { wt[i] = ws + off; off += wt_sz[i]; }  // wt[5] still used (l6 k-major); wt[0] region = Bp
    float* P      = ws + off; off += (size_t)32 * 2048 * 64;  // 4.19M floats
    float* gT_all = ws + off; off += (size_t)10 * 128 * 64;
    float* gT_dec = ws + off; off += 8192;
    float* hT     = ws + off; off += 65536;
    float* cT     = ws + off; off += 65536;
    float* aT1    = ws + off; off += 131072;
    float* aT2    = ws + off; off += 262144;
    float* aT3    = aT1;       // aliases: aT1 dead after l2 stage reads it
    float* aT4    = aT2;       // aliases: aT2 dead after l3 stage reads it
    float* inb1f  = ws + off; off += 147456;                  // 576*1024 bf16 (overlaps deg/xw)
    float* deg    = inb1f;                                    // 40960 floats, dead before inb1 written
    float* xw     = inb1f + 40960;                            // 81920 floats, ditto
    size_t need_bytes = off * sizeof(float);
    if (ws_size < need_bytes) return;

    // bf16 views: inb2..6 alias P (dead during final MFMA phase); 11.2MB <= 16.8MB
    unsigned short* inb1 = (unsigned short*)inb1f;
    unsigned short* inb2 = (unsigned short*)P;
    unsigned short* inb3 = inb2 + (size_t)576 * 2048;
    unsigned short* inb4 = inb3 + (size_t)576 * 4096;
    unsigned short* inb5 = inb4 + (size_t)576 * 2048;
    unsigned short* inb6 = inb5 + (size_t)576 * 1024;
    unsigned short* Bp[6];
    {
        unsigned short* base = (unsigned short*)wt[0];
        size_t boff = 0;
        for (int l = 0; l < 6; ++l) { Bp[l] = base + boff; boff += (size_t)mlp_NO[l] * mlp_K[l]; }
    }
    // split-K fp32 accumulator aliases wt_hh (scratch; no fp32 W stored anymore)
    float* accbuf = wt_hh;   // 4.19M floats >= 576*4096

    hipMemsetAsync(hT, 0, 2 * 65536 * sizeof(float), stream);
    hipMemcpyAsync(out, feat, FRAME_ELEMS * sizeof(float), hipMemcpyDeviceToDevice, stream);

    // ---------- upfront: only wm[5] needs a k-major copy (for finalize3) ----------
    {
        TT8 tasks;
        tasks.t[0] = {wm[5], wt[5], 128, 512, 0};
        for (int j = 1; j < 8; ++j) tasks.t[j] = {wm[5], wt[5], 128, 512, 64};  // never selected
        transpose_all<<<64, 256, 0, stream>>>(tasks);   // (512/32)*(128/32) = 64 blocks
    }

    // ---------- upfront: batched GCN for all 10 input frames ----------
    bgcn_init_xw<<<10 * NTOT / 256, 256, 0, stream>>>(feat, w_gcn, deg, xw);
    bgcn_count<<<10 * NEDGE / 256, 256, 0, stream>>>(ei_in, deg);
    bgcn_node<<<10 * NTOT / 256, 256, 0, stream>>>(b_gcn, deg, xw, gT_all);
    bgcn_scatter_lds<<<80, 256, 0, stream>>>(ei_in, deg, xw, gT_all);

    // ---------- 15 serial steps ----------
    for (int s = 0; s < 15; ++s) {
        const float* gT_s = (s <= 9) ? (gT_all + (size_t)s * 8192) : gT_dec;

        // LSTM: ks 0..7 = hh chunks (K=1024, KC=128, stride 1024), ks 8 = ih (K=128, stride 128)
        gemm_bx8<128><<<dim3(128, 9), 256, 0, stream>>>(hT, gT_s, w_hh, w_ih, 1024, 128, P, 4096, 8);
        lstm_update2<<<HDIM * BSZ / 256, 256, 0, stream>>>(
            P, b_ih, b_hh, hT, cT, (s <= 8) ? inb1 : nullptr, s * 64);

        if (s >= 9) {
            float* frame = out + (size_t)(s + 1) * FRAME_ELEMS;
            // l1: K=1024 NO=2048 KC=64 SK=16
            gemm_bx8<64><<<dim3(64, 16), 256, 0, stream>>>(hT, nullptr, wm[0], nullptr, 1024, 0, P, 2048, 16);
            reduce_relu_kernel<<<2048 * 64 / 256, 256, 0, stream>>>(P, bm[0], aT1, 2048, 16, 1);
            // l2: K=2048 NO=4096 KC=256 (staged 4x64) SK=8
            gemm_bx8<256><<<dim3(128, 8), 256, 0, stream>>>(aT1, nullptr, wm[1], nullptr, 2048, 0, P, 4096, 8);
            reduce_relu_kernel<<<4096 * 64 / 256, 256, 0, stream>>>(P, bm[1], aT2, 4096, 8, 1);
            // l3: K=4096 NO=2048 KC=256 (staged 4x64) SK=16
            gemm_bx8<256><<<dim3(64, 16), 256, 0, stream>>>(aT2, nullptr, wm[2], nullptr, 4096, 0, P, 2048, 16);
            reduce_relu_kernel<<<2048 * 64 / 256, 256, 0, stream>>>(P, bm[2], aT3, 2048, 16, 1);
            // l4: K=2048 NO=1024 KC=128 SK=16
            gemm_bx8<128><<<dim3(32, 16), 256, 0, stream>>>(aT3, nullptr, wm[3], nullptr, 2048, 0, P, 1024, 16);
            reduce_relu_kernel<<<1024 * 64 / 256, 256, 0, stream>>>(P, bm[3], aT4, 1024, 16, 1);
            // l5: K=1024 NO=512 KC=64 SK=16 (partials only; finalize3 reduces)
            gemm_bx8<64><<<dim3(16, 16), 256, 0, stream>>>(aT4, nullptr, wm[4], nullptr, 1024, 0, P, 512, 16);
            // finalize: reduce l5 + l6 GEMM + frame write (+ adjacency + dense GCN)
            finalize3<<<BSZ, 128, 0, stream>>>(P, bm[4], wt[5], bm[5], stats, w_gcn, b_gcn,
                                               frame, gT_dec, (s < 14) ? 1 : 0);
        }
    }

    // ---------- batched encoder MLP (frames 1..9), bf16 MFMA, M=576, split-K ----------
    {
        PTasks pt;
        int goff = 0;
        for (int l = 0; l < 6; ++l) {
            pt.W[l] = wm[l]; pt.Bp[l] = Bp[l]; pt.K[l] = mlp_K[l];
            pt.goff[l] = goff;
            goff += mlp_NO[l] * (mlp_K[l] >> 3);
        }
        pt.goff[6] = goff;
        pack_all<<<(goff + 255) / 256, 256, 0, stream>>>(pt);
    }
    unsigned short* chain_in[6]  = {inb1, inb2, inb3, inb4, inb5, inb6};
    unsigned short* chain_out[6] = {inb2, inb3, inb4, inb5, inb6, nullptr};
    const int mlp_SK[6] = {2, 4, 8, 4, 2, 1};   // KC = K/SK = 512 everywhere
    for (int l = 0; l < 6; ++l) {
        int NO = mlp_NO[l], K = mlp_K[l], SK = mlp_SK[l], KC = K / SK;
        if (l < 5) {
            hipMemsetAsync(accbuf, 0, (size_t)576 * NO * sizeof(float), stream);
            gemm_mfma2<<<dim3(NO / 64, 9, SK), 256, 0, stream>>>(
                chain_in[l], Bp[l], bm[l], nullptr, nullptr, accbuf, K, KC, NO, 0);
            packrelu_kernel<<<(576 * NO + 255) / 256, 256, 0, stream>>>(
                accbuf, bm[l], chain_out[l], NO);
        } else {
            gemm_mfma2<<<dim3(NO / 64, 9, 1), 256, 0, stream>>>(
                chain_in[l], Bp[l], bm[l], nullptr, out + FRAME_ELEMS, nullptr, K, KC, NO, 0);
        }
    }
}

// Round 15
// 1278.856 us; speedup vs baseline: 1.3192x; 1.0366x over previous
//
#include <hip/hip_runtime.h>
#include <hip/hip_bf16.h>
#include <math.h>

// Problem constants
#define NTOT 4096      // B*N nodes
#define NEDGE 65536    // E edges
#define BSZ 64         // batch
#define NN 64          // nodes per trajectory
#define HDIM 1024      // LSTM hidden
#define TIN 10
#define TOUT 6
#define FRAME_ELEMS (NTOT * 2)   // 8192 floats per frame

typedef short s16x8 __attribute__((ext_vector_type(8)));
typedef float f32x4 __attribute__((ext_vector_type(4)));

__device__ __forceinline__ unsigned short f2bf(float f) {
    union { float f; unsigned u; } x; x.f = f;
    unsigned r = x.u + 0x7fffu + ((x.u >> 16) & 1u);
    return (unsigned short)(r >> 16);
}

// ==================== weight transpose (task list; only used for wm[5]) ====================
struct TT { const float* W; float* WT; int NO; int K; int toff; };
struct TT8 { TT t[8]; };

__global__ __launch_bounds__(256) void transpose_all(TT8 tasks) {
    int bid = blockIdx.x;
    int ti = 0;
    #pragma unroll
    for (int j = 1; j < 8; ++j) if (bid >= tasks.t[j].toff) ti = j;
    TT tk = tasks.t[ti];
    int local = bid - tk.toff;
    int tilesK = tk.K >> 5;
    int kb = local % tilesK, nb = local / tilesK;
    int k0 = kb * 32, n0 = nb * 32;
    __shared__ float t[32][33];
    int tx = threadIdx.x & 31, ty = threadIdx.x >> 5;  // 32 x 8
    #pragma unroll
    for (int i = 0; i < 4; ++i)
        t[ty + i * 8][tx] = tk.W[(size_t)(n0 + ty + i * 8) * tk.K + k0 + tx];
    __syncthreads();
    #pragma unroll
    for (int i = 0; i < 4; ++i)
        tk.WT[(size_t)(k0 + ty + i * 8) * tk.NO + n0 + tx] = t[tx][ty + i * 8];
}

// ==================== batched GCN over 10 input frames ====================

__global__ void bgcn_init_xw(const float* __restrict__ feat, const float* __restrict__ wg,
                             float* __restrict__ deg, float* __restrict__ xw) {
    int i = blockIdx.x * blockDim.x + threadIdx.x;
    if (i >= 10 * NTOT) return;
    deg[i] = 1.0f;
    float x0 = feat[i * 2], x1 = feat[i * 2 + 1];
    xw[i * 2]     = x0 * wg[0] + x1 * wg[1];
    xw[i * 2 + 1] = x0 * wg[2] + x1 * wg[3];
}

__global__ void bgcn_count(const int* __restrict__ ei, float* __restrict__ deg) {
    int e = blockIdx.x * blockDim.x + threadIdx.x;
    if (e >= 10 * NEDGE) return;
    int t = e >> 16, el = e & 65535;
    int dst = ei[t * 2 * NEDGE + NEDGE + el];
    atomicAdd(&deg[t * NTOT + dst], 1.0f);
}

__global__ void bgcn_node(const float* __restrict__ bg, float* __restrict__ deg,
                          const float* __restrict__ xw, float* __restrict__ gT_all) {
    int i = blockIdx.x * blockDim.x + threadIdx.x;
    if (i >= 10 * NTOT) return;
    float dinv = rsqrtf(deg[i]);
    deg[i] = dinv;
    int t = i >> 12, node = i & 4095;
    int b = node >> 6, nn = node & 63;
    float w2 = dinv * dinv;
    gT_all[t * 8192 + (nn * 2 + 0) * 64 + b] = xw[i * 2]     * w2 + bg[0];
    gT_all[t * 8192 + (nn * 2 + 1) * 64 + b] = xw[i * 2 + 1] * w2 + bg[1];
}

// LDS-accumulated edge scatter: 16 blocks per frame
__global__ __launch_bounds__(256) void bgcn_scatter_lds(const int* __restrict__ ei,
                                                        const float* __restrict__ dinv,
                                                        const float* __restrict__ xw,
                                                        float* __restrict__ gT_all) {
    __shared__ float sg[8192];
    int t = blockIdx.x >> 4;
    int chunk = blockIdx.x & 15;
    for (int i = threadIdx.x; i < 8192; i += 256) sg[i] = 0.f;
    __syncthreads();
    const int* eis = ei + t * 2 * NEDGE;
    int e0 = chunk * 4096;
    for (int e = e0 + threadIdx.x; e < e0 + 4096; e += 256) {
        int s = eis[e];
        int d = eis[NEDGE + e];
        float w = dinv[t * NTOT + s] * dinv[t * NTOT + d];
        int b = d >> 6, nn = d & 63;
        atomicAdd(&sg[(nn * 2 + 0) * 64 + b], xw[(t * NTOT + s) * 2]     * w);
        atomicAdd(&sg[(nn * 2 + 1) * 64 + b], xw[(t * NTOT + s) * 2 + 1] * w);
    }
    __syncthreads();
    float* gt = gT_all + t * 8192;
    for (int i = threadIdx.x; i < 8192; i += 256) {
        float v = sg[i];
        if (v != 0.f) atomicAdd(&gt[i], v);
    }
}

// ==================== broadcast-x GEMM v9: 2 n-rows x 4 m per thread, row-major W ====================
// P[ks][n][m] = sum over k-chunk ks of in[m][k] * W[n][k], W row-major (NO, strideW).
// thread: ns = tid>>4 (16 pairs -> 32 n per block), q = tid&15 -> m in [q*4, q*4+4).
// Per k: 1 ds_read_b128 + 8 fmac -> VALU-bound (bx8 was 2 b128 per 8 fmac = LDS-bound).
template<int KC>
__global__ __launch_bounds__(256) void gemm_bx9(
    const float* __restrict__ inT, const float* __restrict__ inT2,
    const float* __restrict__ W1,  const float* __restrict__ W2,
    int st1, int st2,
    float* __restrict__ P, int NO, int SK1)
{
    constexpr int STG = (KC > 64) ? 64 : KC;
    __shared__ float xs[STG * 64];   // <=16KB
    int tid = threadIdx.x;
    int ks = blockIdx.y;
    const float* xsrc; const float* wrow; int koff, strideW;
    if (ks < SK1) { xsrc = inT  + (size_t)ks * KC * 64;         wrow = W1; koff = ks * KC;         strideW = st1; }
    else          { xsrc = inT2 + (size_t)(ks - SK1) * KC * 64; wrow = W2; koff = (ks - SK1) * KC; strideW = st2; }
    int ns = tid >> 4, q = tid & 15;
    int n = blockIdx.x * 32 + ns * 2;
    const float* w0 = wrow + (size_t)n * strideW + koff;
    const float* w1 = w0 + strideW;
    const float* xq = xs + q * 4;
    float acc0[4] = {0.f, 0.f, 0.f, 0.f};
    float acc1[4] = {0.f, 0.f, 0.f, 0.f};

    for (int kb = 0; kb < KC; kb += STG) {
        if (kb) __syncthreads();
        #pragma unroll
        for (int i = 0; i < STG / 16; ++i)
            ((float4*)xs)[tid + i * 256] = ((const float4*)(xsrc + (size_t)kb * 64))[tid + i * 256];
        __syncthreads();
        const float* p0 = w0 + kb;
        const float* p1 = w1 + kb;
        float4 a0 = *(const float4*)(p0);
        float4 a1 = *(const float4*)(p1);
        float4 b0 = *(const float4*)(p0 + 4);
        float4 b1 = *(const float4*)(p1 + 4);
        for (int k = 0; k < STG; k += 8) {
            float4 c0, c1, d0, d1;
            if (k + 8 < STG) {
                c0 = *(const float4*)(p0 + k + 8);
                c1 = *(const float4*)(p1 + k + 8);
                d0 = *(const float4*)(p0 + k + 12);
                d1 = *(const float4*)(p1 + k + 12);
            }
            // consume a0/a1: k .. k+3
            #pragma unroll
            for (int kk = 0; kk < 4; ++kk) {
                float4 x = *(const float4*)(xq + (k + kk) * 64);
                float wa = (kk == 0) ? a0.x : (kk == 1) ? a0.y : (kk == 2) ? a0.z : a0.w;
                float wb = (kk == 0) ? a1.x : (kk == 1) ? a1.y : (kk == 2) ? a1.z : a1.w;
                acc0[0] = fmaf(wa, x.x, acc0[0]); acc0[1] = fmaf(wa, x.y, acc0[1]);
                acc0[2] = fmaf(wa, x.z, acc0[2]); acc0[3] = fmaf(wa, x.w, acc0[3]);
                acc1[0] = fmaf(wb, x.x, acc1[0]); acc1[1] = fmaf(wb, x.y, acc1[1]);
                acc1[2] = fmaf(wb, x.z, acc1[2]); acc1[3] = fmaf(wb, x.w, acc1[3]);
            }
            // consume b0/b1: k+4 .. k+7
            #pragma unroll
            for (int kk = 0; kk < 4; ++kk) {
                float4 x = *(const float4*)(xq + (k + 4 + kk) * 64);
                float wa = (kk == 0) ? b0.x : (kk == 1) ? b0.y : (kk == 2) ? b0.z : b0.w;
                float wb = (kk == 0) ? b1.x : (kk == 1) ? b1.y : (kk == 2) ? b1.z : b1.w;
                acc0[0] = fmaf(wa, x.x, acc0[0]); acc0[1] = fmaf(wa, x.y, acc0[1]);
                acc0[2] = fmaf(wa, x.z, acc0[2]); acc0[3] = fmaf(wa, x.w, acc0[3]);
                acc1[0] = fmaf(wb, x.x, acc1[0]); acc1[1] = fmaf(wb, x.y, acc1[1]);
                acc1[2] = fmaf(wb, x.z, acc1[2]); acc1[3] = fmaf(wb, x.w, acc1[3]);
            }
            a0 = c0; a1 = c1; b0 = d0; b1 = d1;
        }
    }
    float* pp = P + ((size_t)ks * NO + n) * 64 + q * 4;
    *(float4*)pp        = make_float4(acc0[0], acc0[1], acc0[2], acc0[3]);
    *(float4*)(pp + 64) = make_float4(acc1[0], acc1[1], acc1[2], acc1[3]);
}

// ==================== reduce partials + bias (+relu) -> aT (NO,64) ====================
__global__ void reduce_relu_kernel(const float* __restrict__ P,
                                   const float* __restrict__ bias,
                                   float* __restrict__ aT,
                                   int NO, int SK, int relu) {
    int idx = blockIdx.x * blockDim.x + threadIdx.x;
    if (idx >= NO * 64) return;
    int n = idx >> 6;
    float v = bias[n];
    for (int ks = 0; ks < SK; ++ks) v += P[(size_t)ks * NO * 64 + idx];
    if (relu) v = fmaxf(v, 0.f);
    aT[idx] = v;
}

// ==================== LSTM pointwise from 9 partials (+ optional bf16 h-stash) ====================
__global__ void lstm_update2(const float* __restrict__ P,
                             const float* __restrict__ b_ih, const float* __restrict__ b_hh,
                             float* __restrict__ hT, float* __restrict__ cT,
                             unsigned short* __restrict__ stash, int mbase) {
    int t = blockIdx.x * blockDim.x + threadIdx.x;
    if (t >= HDIM * BSZ) return;
    int j = t >> 6, b = t & 63;
    float g4[4];
    #pragma unroll
    for (int gi = 0; gi < 4; ++gi) {
        int row = gi * HDIM + j;
        float v = b_ih[row] + b_hh[row];
        size_t base = (size_t)row * 64 + b;
        #pragma unroll
        for (int ks = 0; ks < 9; ++ks) v += P[(size_t)ks * 4096 * 64 + base];
        g4[gi] = v;
    }
    float si = 1.f / (1.f + expf(-g4[0]));
    float sf = 1.f / (1.f + expf(-g4[1]));
    float gg = tanhf(g4[2]);
    float so = 1.f / (1.f + expf(-g4[3]));
    float cn = sf * cT[t] + si * gg;
    cT[t] = cn;
    float h = so * tanhf(cn);
    hT[t] = h;
    if (stash) stash[(size_t)(mbase + b) * HDIM + j] = f2bf(h);
}

// ==================== finalize3: reduce l5 partials + l6 GEMM + frame (+adj + dense GCN) ====================
__global__ void finalize3(const float* __restrict__ P, const float* __restrict__ b5,
                          const float* __restrict__ wt5, const float* __restrict__ b6,
                          const float* __restrict__ stats, const float* __restrict__ wg,
                          const float* __restrict__ bg,
                          float* __restrict__ frame, float* __restrict__ gT, int dec)
{
    int b = blockIdx.x;
    int n = threadIdx.x;   // 0..127
    __shared__ float a5[512];
    __shared__ float p[128];
    __shared__ float f0[NN], f1[NN], sxw0[NN], sxw1[NN], sdinv[NN];
    __shared__ int ex[NN];
    #pragma unroll
    for (int j = 0; j < 4; ++j) {
        int k = n * 4 + j;
        float v = b5[k];
        #pragma unroll 4
        for (int ks = 0; ks < 16; ++ks) v += P[((size_t)ks * 512 + k) * 64 + b];
        a5[k] = fmaxf(v, 0.f);
    }
    __syncthreads();
    float acc = b6[n];
    for (int k = 0; k < 512; ++k) acc = fmaf(a5[k], wt5[k * 128 + n], acc);
    p[n] = acc;
    frame[b * 128 + n] = acc;
    if (!dec) return;
    __syncthreads();
    int i = n;
    if (i < NN) {
        float p0 = p[i * 2], p1 = p[i * 2 + 1];
        float d0 = p0 * stats[0] + stats[2];
        float d1 = p1 * stats[1] + stats[3];
        f0[i] = d0; f1[i] = d1;
        ex[i] = (d0 > 0.04f) && (d1 > 0.04f);
        sxw0[i] = p0 * wg[0] + p1 * wg[1];
        sxw1[i] = p0 * wg[2] + p1 * wg[3];
    }
    __syncthreads();
    if (i < NN) {
        float fi0 = f0[i], fi1 = f1[i];
        int exi = ex[i];
        float deg = 0.f;
        for (int j = 0; j < NN; ++j) {
            float dx = fi0 - f0[j], dy = fi1 - f1[j];
            float a = (i == j) ? 1.0f :
                      ((dx * dx + dy * dy <= 100.0f && exi && ex[j]) ? 1.0f : 0.0f);
            deg += a;
        }
        sdinv[i] = rsqrtf(deg);
    }
    __syncthreads();
    if (i < NN) {
        float fi0 = f0[i], fi1 = f1[i];
        int exi = ex[i];
        float a0 = 0.f, a1 = 0.f;
        for (int j = 0; j < NN; ++j) {
            float dx = fi0 - f0[j], dy = fi1 - f1[j];
            float a = (i == j) ? 1.0f :
                      ((dx * dx + dy * dy <= 100.0f && exi && ex[j]) ? 1.0f : 0.0f);
            float an = a * sdinv[j];
            a0 += an * sxw0[j];
            a1 += an * sxw1[j];
        }
        float di = sdinv[i];
        gT[(i * 2 + 0) * 64 + b] = a0 * di + bg[0];
        gT[(i * 2 + 1) * 64 + b] = a1 * di + bg[1];
    }
}

// ==================== combined bf16 pack (coalesced writes: consecutive g -> consecutive n) ====================
struct PTasks {
    const float* W[6]; unsigned short* Bp[6]; int K[6]; int NO[6]; int goff[7];
};
__global__ void pack_all(PTasks pt) {
    int g = blockIdx.x * blockDim.x + threadIdx.x;
    if (g >= pt.goff[6]) return;
    int l = 0;
    #pragma unroll
    for (int j = 1; j < 6; ++j) if (g >= pt.goff[j]) l = j;
    int local = g - pt.goff[l];
    int NO = pt.NO[l];
    int n  = local % NO;        // consecutive threads -> consecutive n -> coalesced 16B writes
    int kg = local / NO;
    const float* src = pt.W[l] + (size_t)n * pt.K[l] + (size_t)kg * 8;
    unsigned short tmp[8];
    #pragma unroll
    for (int j = 0; j < 8; ++j) tmp[j] = f2bf(src[j]);
    unsigned short* dst = pt.Bp[l] + ((size_t)kg * NO + n) * 8;
    *(s16x8*)dst = *(const s16x8*)tmp;
}

// ==================== batched MFMA MLP layer v2 + split-K (blockIdx.z) ====================
__global__ __launch_bounds__(256) void gemm_mfma2(
    const unsigned short* __restrict__ inb,
    const unsigned short* __restrict__ Bp,
    const float* __restrict__ bias,
    unsigned short* __restrict__ outb,
    float* __restrict__ frames,
    float* __restrict__ accbuf,
    int K, int KC, int NO, int relu)
{
    __shared__ unsigned short A[64][72];
    int tid = threadIdx.x;
    int lane = tid & 63;
    int w = tid >> 6;
    int m0 = blockIdx.y * 64;
    int nb = blockIdx.x * 64;
    int koff = blockIdx.z * KC;
    int l15 = lane & 15;
    int lq  = lane >> 4;
    int n = nb + w * 16 + l15;
    int sm = tid >> 3, skq = tid & 7;
    const unsigned short* bpb = Bp + (size_t)(koff >> 3) * NO * 8;
    f32x4 acc[4] = {};

    {
        s16x8 a0 = *(const s16x8*)&inb[(size_t)(m0 + sm) * K + koff + skq * 8];
        s16x8 a1 = *(const s16x8*)&inb[(size_t)(m0 + sm + 32) * K + koff + skq * 8];
        *(s16x8*)&A[sm][skq * 8] = a0;
        *(s16x8*)&A[sm + 32][skq * 8] = a1;
    }
    __syncthreads();
    s16x8 b0 = *(const s16x8*)&bpb[((size_t)(0 + lq) * NO + n) * 8];
    s16x8 b1 = *(const s16x8*)&bpb[((size_t)(4 + lq) * NO + n) * 8];

    int nk = KC >> 6;
    for (int t = 0; t < nk; ++t) {
        s16x8 na0, na1, nb0, nb1;
        bool more = (t + 1 < nk);
        if (more) {
            int ko = koff + (t + 1) * 64;
            na0 = *(const s16x8*)&inb[(size_t)(m0 + sm) * K + ko + skq * 8];
            na1 = *(const s16x8*)&inb[(size_t)(m0 + sm + 32) * K + ko + skq * 8];
            int kg = (t + 1) * 8;
            nb0 = *(const s16x8*)&bpb[((size_t)(kg + lq) * NO + n) * 8];
            nb1 = *(const s16x8*)&bpb[((size_t)(kg + 4 + lq) * NO + n) * 8];
        }
        #pragma unroll
        for (int s = 0; s < 4; ++s) {
            s16x8 af = *(const s16x8*)&A[s * 16 + l15][lq * 8];
            acc[s] = __builtin_amdgcn_mfma_f32_16x16x32_bf16(af, b0, acc[s], 0, 0, 0);
        }
        #pragma unroll
        for (int s = 0; s < 4; ++s) {
            s16x8 af = *(const s16x8*)&A[s * 16 + l15][32 + lq * 8];
            acc[s] = __builtin_amdgcn_mfma_f32_16x16x32_bf16(af, b1, acc[s], 0, 0, 0);
        }
        if (more) {
            __syncthreads();
            *(s16x8*)&A[sm][skq * 8] = na0;
            *(s16x8*)&A[sm + 32][skq * 8] = na1;
            __syncthreads();
            b0 = nb0; b1 = nb1;
        }
    }
    if (accbuf) {
        #pragma unroll
        for (int s = 0; s < 4; ++s) {
            #pragma unroll
            for (int r = 0; r < 4; ++r) {
                int m = m0 + s * 16 + lq * 4 + r;
                atomicAdd(&accbuf[(size_t)m * NO + n], acc[s][r]);
            }
        }
        return;
    }
    float bn = bias[n];
    #pragma unroll
    for (int s = 0; s < 4; ++s) {
        #pragma unroll
        for (int r = 0; r < 4; ++r) {
            int m = m0 + s * 16 + lq * 4 + r;
            float v = acc[s][r] + bn;
            if (relu) v = fmaxf(v, 0.f);
            if (outb) outb[(size_t)m * NO + n] = f2bf(v);
            if (frames && m < 576) {
                int f = m >> 6, b = m & 63;
                frames[(size_t)f * FRAME_ELEMS + b * 128 + n] = v;
            }
        }
    }
}

// ==================== bias+relu+pack for split-K accumulated layers ====================
__global__ void packrelu_kernel(const float* __restrict__ acc, const float* __restrict__ bias,
                                unsigned short* __restrict__ outb, int NO) {
    int idx = blockIdx.x * blockDim.x + threadIdx.x;
    if (idx >= 576 * NO) return;
    int n = idx & (NO - 1);   // NO is a power of 2
    float v = acc[idx] + bias[n];
    outb[idx] = f2bf(fmaxf(v, 0.f));
}

// ==================== host ====================

extern "C" void kernel_launch(void* const* d_in, const int* in_sizes, int n_in,
                              void* d_out, int out_size, void* d_ws, size_t ws_size,
                              hipStream_t stream) {
    const float* feat   = (const float*)d_in[0];
    const int*   ei_in  = (const int*)d_in[1];
    const float* stats  = (const float*)d_in[4];
    const float* w_gcn  = (const float*)d_in[5];
    const float* b_gcn  = (const float*)d_in[6];
    const float* w_ih   = (const float*)d_in[7];
    const float* w_hh   = (const float*)d_in[8];
    const float* b_ih   = (const float*)d_in[9];
    const float* b_hh   = (const float*)d_in[10];
    const float* wm[6], *bm[6];
    for (int i = 0; i < 6; ++i) { wm[i] = (const float*)d_in[11 + 2*i]; bm[i] = (const float*)d_in[12 + 2*i]; }
    const int mlp_K[6]  = {1024, 2048, 4096, 2048, 1024, 512};
    const int mlp_NO[6] = {2048, 4096, 2048, 1024, 512, 128};

    float* out = (float*)d_out;
    float* ws  = (float*)d_ws;

    // ---------- workspace layout (floats) — identical offsets to round 14 ----------
    size_t off = 0;
    float* wt_ih = ws + off; off += (size_t)128 * 4096;        // unused scratch
    float* wt_hh = ws + off; off += (size_t)1024 * 4096;       // accbuf aliases this
    float* wt[6];
    const size_t wt_sz[6] = {(size_t)1024*2048, (size_t)2048*4096, (size_t)4096*2048,
                             (size_t)2048*1024, (size_t)1024*512, (size_t)512*128};
    for (int i = 0; i < 6; ++i) { wt[i] = ws + off; off += wt_sz[i]; }  // wt[5] used (l6 k-major); wt[0] region = Bp
    float* P      = ws + off; off += (size_t)32 * 2048 * 64;  // 4.19M floats
    float* gT_all = ws + off; off += (size_t)10 * 128 * 64;
    float* gT_dec = ws + off; off += 8192;
    float* hT     = ws + off; off += 65536;
    float* cT     = ws + off; off += 65536;
    float* aT1    = ws + off; off += 131072;
    float* aT2    = ws + off; off += 262144;
    float* aT3    = aT1;       // aliases: aT1 dead after l2 stage reads it
    float* aT4    = aT2;       // aliases: aT2 dead after l3 stage reads it
    float* inb1f  = ws + off; off += 147456;                  // 576*1024 bf16 (overlaps deg/xw)
    float* deg    = inb1f;                                    // 40960 floats, dead before inb1 written
    float* xw     = inb1f + 40960;                            // 81920 floats, ditto
    size_t need_bytes = off * sizeof(float);
    if (ws_size < need_bytes) return;

    // bf16 views: inb2..6 alias P (dead during final MFMA phase); 11.2MB <= 16.8MB
    unsigned short* inb1 = (unsigned short*)inb1f;
    unsigned short* inb2 = (unsigned short*)P;
    unsigned short* inb3 = inb2 + (size_t)576 * 2048;
    unsigned short* inb4 = inb3 + (size_t)576 * 4096;
    unsigned short* inb5 = inb4 + (size_t)576 * 2048;
    unsigned short* inb6 = inb5 + (size_t)576 * 1024;
    unsigned short* Bp[6];
    {
        unsigned short* base = (unsigned short*)wt[0];
        size_t boff = 0;
        for (int l = 0; l < 6; ++l) { Bp[l] = base + boff; boff += (size_t)mlp_NO[l] * mlp_K[l]; }
    }
    // split-K fp32 accumulator aliases wt_hh (scratch)
    float* accbuf = wt_hh;   // 4.19M floats >= 576*4096

    hipMemsetAsync(hT, 0, 2 * 65536 * sizeof(float), stream);
    hipMemcpyAsync(out, feat, FRAME_ELEMS * sizeof(float), hipMemcpyDeviceToDevice, stream);

    // ---------- upfront: only wm[5] needs a k-major copy (for finalize3) ----------
    {
        TT8 tasks;
        tasks.t[0] = {wm[5], wt[5], 128, 512, 0};
        for (int j = 1; j < 8; ++j) tasks.t[j] = {wm[5], wt[5], 128, 512, 64};  // never selected
        transpose_all<<<64, 256, 0, stream>>>(tasks);   // (512/32)*(128/32) = 64 blocks
    }

    // ---------- upfront: batched GCN for all 10 input frames ----------
    bgcn_init_xw<<<10 * NTOT / 256, 256, 0, stream>>>(feat, w_gcn, deg, xw);
    bgcn_count<<<10 * NEDGE / 256, 256, 0, stream>>>(ei_in, deg);
    bgcn_node<<<10 * NTOT / 256, 256, 0, stream>>>(b_gcn, deg, xw, gT_all);
    bgcn_scatter_lds<<<160, 256, 0, stream>>>(ei_in, deg, xw, gT_all);

    // ---------- 15 serial steps ----------
    for (int s = 0; s < 15; ++s) {
        const float* gT_s = (s <= 9) ? (gT_all + (size_t)s * 8192) : gT_dec;

        // LSTM: ks 0..7 = hh chunks (K=1024, KC=128, stride 1024), ks 8 = ih (K=128, stride 128)
        gemm_bx9<128><<<dim3(128, 9), 256, 0, stream>>>(hT, gT_s, w_hh, w_ih, 1024, 128, P, 4096, 8);
        lstm_update2<<<HDIM * BSZ / 256, 256, 0, stream>>>(
            P, b_ih, b_hh, hT, cT, (s <= 8) ? inb1 : nullptr, s * 64);

        if (s >= 9) {
            float* frame = out + (size_t)(s + 1) * FRAME_ELEMS;
            // l1: K=1024 NO=2048 KC=64 SK=16
            gemm_bx9<64><<<dim3(64, 16), 256, 0, stream>>>(hT, nullptr, wm[0], nullptr, 1024, 0, P, 2048, 16);
            reduce_relu_kernel<<<2048 * 64 / 256, 256, 0, stream>>>(P, bm[0], aT1, 2048, 16, 1);
            // l2: K=2048 NO=4096 KC=256 (staged 4x64) SK=8
            gemm_bx9<256><<<dim3(128, 8), 256, 0, stream>>>(aT1, nullptr, wm[1], nullptr, 2048, 0, P, 4096, 8);
            reduce_relu_kernel<<<4096 * 64 / 256, 256, 0, stream>>>(P, bm[1], aT2, 4096, 8, 1);
            // l3: K=4096 NO=2048 KC=256 (staged 4x64) SK=16
            gemm_bx9<256><<<dim3(64, 16), 256, 0, stream>>>(aT2, nullptr, wm[2], nullptr, 4096, 0, P, 2048, 16);
            reduce_relu_kernel<<<2048 * 64 / 256, 256, 0, stream>>>(P, bm[2], aT3, 2048, 16, 1);
            // l4: K=2048 NO=1024 KC=128 SK=16
            gemm_bx9<128><<<dim3(32, 16), 256, 0, stream>>>(aT3, nullptr, wm[3], nullptr, 2048, 0, P, 1024, 16);
            reduce_relu_kernel<<<1024 * 64 / 256, 256, 0, stream>>>(P, bm[3], aT4, 1024, 16, 1);
            // l5: K=1024 NO=512 KC=64 SK=16 (partials only; finalize3 reduces)
            gemm_bx9<64><<<dim3(16, 16), 256, 0, stream>>>(aT4, nullptr, wm[4], nullptr, 1024, 0, P, 512, 16);
            // finalize: reduce l5 + l6 GEMM + frame write (+ adjacency + dense GCN)
            finalize3<<<BSZ, 128, 0, stream>>>(P, bm[4], wt[5], bm[5], stats, w_gcn, b_gcn,
                                               frame, gT_dec, (s < 14) ? 1 : 0);
        }
    }

    // ---------- batched encoder MLP (frames 1..9), bf16 MFMA, M=576, split-K ----------
    {
        PTasks pt;
        int goff = 0;
        for (int l = 0; l < 6; ++l) {
            pt.W[l] = wm[l]; pt.Bp[l] = Bp[l]; pt.K[l] = mlp_K[l]; pt.NO[l] = mlp_NO[l];
            pt.goff[l] = goff;
            goff += mlp_NO[l] * (mlp_K[l] >> 3);
        }
        pt.goff[6] = goff;
        pack_all<<<(goff + 255) / 256, 256, 0, stream>>>(pt);
    }
    unsigned short* chain_in[6]  = {inb1, inb2, inb3, inb4, inb5, inb6};
    unsigned short* chain_out[6] = {inb2, inb3, inb4, inb5, inb6, nullptr};
    const int mlp_SK[6] = {2, 4, 8, 4, 2, 1};   // KC = K/SK = 512 everywhere
    for (int l = 0; l < 6; ++l) {
        int NO = mlp_NO[l], K = mlp_K[l], SK = mlp_SK[l], KC = K / SK;
        if (l < 5) {
            hipMemsetAsync(accbuf, 0, (size_t)576 * NO * sizeof(float), stream);
            gemm_mfma2<<<dim3(NO / 64, 9, SK), 256, 0, stream>>>(
                chain_in[l], Bp[l], bm[l], nullptr, nullptr, accbuf, K, KC, NO, 0);
            packrelu_kernel<<<(576 * NO + 255) / 256, 256, 0, stream>>>(
                accbuf, bm[l], chain_out[l], NO);
        } else {
            gemm_mfma2<<<dim3(NO / 64, 9, 1), 256, 0, stream>>>(
                chain_in[l], Bp[l], bm[l], nullptr, out + FRAME_ELEMS, nullptr, K, KC, NO, 0);
        }
    }
}